// Round 5
// baseline (28272.748 us; speedup 1.0000x reference)
//
#include <hip/hip_runtime.h>

typedef unsigned short u16;
typedef unsigned int u32;

#define LN_EPS 1e-5f

__device__ __forceinline__ float bf2f(u16 u) {
    union { u32 i; float f; } v; v.i = ((u32)u) << 16; return v.f;
}
__device__ __forceinline__ u16 f2bf(float f) {
    union { u32 i; float f; } v; v.f = f;
    u32 x = v.i;
    return (u16)((x + 0x7fffu + ((x >> 16) & 1u)) >> 16);
}
__device__ __forceinline__ int clampi(int v, int lo, int hi) {
    return v < lo ? lo : (v > hi ? hi : v);
}

// Diagnostic fill (f32).
__global__ void k_fill(float* __restrict__ out, int nel, float val) {
    int i = blockIdx.x * blockDim.x + threadIdx.x;
    if (i < nel) out[i] = val;
}

// ---------------- preprocessing ----------------
__global__ void k_zero(int* p, int n) {
    int i = blockIdx.x * blockDim.x + threadIdx.x;
    if (i < n) p[i] = 0;
}

// Detect int64 (odd int32 words all zero) vs int32 upload of edge_index.
__global__ void k_detect(const int* __restrict__ ei, int E, int* __restrict__ flag) {
    __shared__ int any;
    if (threadIdx.x == 0) any = 0;
    __syncthreads();
    int lim = (E < 4096) ? E : 4096;
    int v = 0;
    for (int i = threadIdx.x; i < lim; i += 256) v |= ei[2 * i + 1];
    if (v) atomicOr(&any, 1);
    __syncthreads();
    if (threadIdx.x == 0) flag[0] = (any == 0) ? 1 : 0;
}

__global__ void k_hist(const int* __restrict__ ei, const int* __restrict__ flag,
                       int* __restrict__ deg, int E, int n) {
    int e = blockIdx.x * blockDim.x + threadIdx.x;
    if (e < E) {
        int d = flag[0] ? ei[2 * ((size_t)E + e)] : ei[(size_t)E + e];
        atomicAdd(&deg[clampi(d, 0, n - 1)], 1);
    }
}

__global__ void k_scan1(const int* __restrict__ deg, int* __restrict__ offs,
                        int* __restrict__ bsum, int n) {
    __shared__ int s[256];
    int t = threadIdx.x;
    int i = blockIdx.x * 256 + t;
    int v = (i < n) ? deg[i] : 0;
    s[t] = v; __syncthreads();
    for (int off = 1; off < 256; off <<= 1) {
        int x = (t >= off) ? s[t - off] : 0;
        __syncthreads();
        s[t] += x;
        __syncthreads();
    }
    if (i < n) offs[i] = s[t] - v;
    if (t == 255) bsum[blockIdx.x] = s[255];
}

__global__ void k_scan2(int* bsum, int nb) {
    __shared__ int s[256];
    int t = threadIdx.x;
    int v = (t < nb) ? bsum[t] : 0;
    s[t] = v; __syncthreads();
    for (int off = 1; off < 256; off <<= 1) {
        int x = (t >= off) ? s[t - off] : 0;
        __syncthreads();
        s[t] += x;
        __syncthreads();
    }
    if (t < nb) bsum[t] = s[t] - v;
}

__global__ void k_scan3(int* __restrict__ offs, const int* __restrict__ bsum,
                        int* __restrict__ cursor, int n, int E) {
    int i = blockIdx.x * 256 + threadIdx.x;
    if (i < n) {
        int v = offs[i] + bsum[blockIdx.x];
        offs[i] = v;
        cursor[i] = v;
    }
    if (i == 0) offs[n] = E;
}

__global__ void k_scatter(const int* __restrict__ ei, const int* __restrict__ flag,
                          int* __restrict__ cursor,
                          int* __restrict__ perm, int* __restrict__ srcs,
                          int* __restrict__ dsts, int E, int n) {
    int e = blockIdx.x * blockDim.x + threadIdx.x;
    if (e < E) {
        int sv, dv;
        if (flag[0]) {
            sv = ei[2 * (size_t)e];
            dv = ei[2 * ((size_t)E + e)];
        } else {
            sv = ei[e];
            dv = ei[(size_t)E + e];
        }
        sv = clampi(sv, 0, n - 1);
        dv = clampi(dv, 0, n - 1);
        int p = clampi(atomicAdd(&cursor[dv], 1), 0, E - 1);
        perm[p] = e;
        srcs[p] = sv;
        dsts[p] = dv;
    }
}

// Convert W1 (f32) -> bf16 workspace copy (so it fits in 48 KB LDS).
__global__ void k_wcvt(const float* __restrict__ Wf, u16* __restrict__ Wb, int total) {
    int i = blockIdx.x * blockDim.x + threadIdx.x;
    if (i < total) Wb[i] = f2bf(Wf[i]);
}

// ---------------- encoders (f32 inputs) ----------------
__global__ __launch_bounds__(256) void k_node_enc(
    const float* __restrict__ x, const float* __restrict__ W, const float* __restrict__ bias,
    float* __restrict__ h, u16* __restrict__ hn, int n) {
    __shared__ float sW[128 * 64];   // 32 KB
    int t = threadIdx.x;
    for (int i = t; i < 128 * 64; i += 256) sW[i] = W[i];
    __syncthreads();
    int wid = t >> 6, lane = t & 63;
    float bc = bias[lane];
    for (int row = blockIdx.x * 4 + wid; row < n; row += gridDim.x * 4) {
        float2 pr = ((const float2*)(x + (size_t)row * 128))[lane];
        float acc = bc;
#pragma unroll
        for (int k = 0; k < 128; k++) {
            float f = __shfl((k & 1) ? pr.y : pr.x, k >> 1);
            acc += f * sW[k * 64 + lane];
        }
        h[(size_t)row * 64 + lane] = acc;
        hn[(size_t)row * 64 + lane] = f2bf(acc);
    }
}

__global__ __launch_bounds__(256) void k_edge_enc(
    const float* __restrict__ ea, const int* __restrict__ perm,
    const float* __restrict__ W, const float* __restrict__ bias,
    u16* __restrict__ e_s, int E) {
    __shared__ float sW[16 * 64];    // 4 KB
    int t = threadIdx.x;
    for (int i = t; i < 16 * 64; i += 256) sW[i] = W[i];
    __syncthreads();
    int wid = t >> 6, lane = t & 63;
    float bc = bias[lane];
    for (int pos = blockIdx.x * 4 + wid; pos < E; pos += gridDim.x * 4) {
        int e = perm[pos];
        float pr = (lane < 16) ? ea[(size_t)e * 16 + lane] : 0.f;
        float acc = bc;
#pragma unroll
        for (int k = 0; k < 16; k++) {
            float f = __shfl(pr, k);
            acc += f * sW[k * 64 + lane];
        }
        e_s[(size_t)pos * 64 + lane] = f2bf(acc);
    }
}

// ---------------- layernorm: bf16-out (hn producer) and f32-out (final) ----------------
__global__ __launch_bounds__(256) void k_lnorm_bf(
    const float* __restrict__ h, const float* __restrict__ g, const float* __restrict__ b,
    u16* __restrict__ out, int n) {
    int t = threadIdx.x, wid = t >> 6, lane = t & 63;
    float gc = g[lane], bc = b[lane];
    for (int row = blockIdx.x * 4 + wid; row < n; row += gridDim.x * 4) {
        float v = h[(size_t)row * 64 + lane];
        float s = v;
#pragma unroll
        for (int o = 32; o > 0; o >>= 1) s += __shfl_xor(s, o);
        float mu = s * (1.f / 64.f);
        float d = v - mu;
        float s2 = d * d;
#pragma unroll
        for (int o = 32; o > 0; o >>= 1) s2 += __shfl_xor(s2, o);
        float inv = rsqrtf(s2 * (1.f / 64.f) + LN_EPS);
        float r = fmaxf(d * inv * gc + bc, 0.f);
        out[(size_t)row * 64 + lane] = f2bf(r);
    }
}

__global__ __launch_bounds__(256) void k_lnorm_out(
    const float* __restrict__ h, const float* __restrict__ g, const float* __restrict__ b,
    float* __restrict__ out, int n) {
    int t = threadIdx.x, wid = t >> 6, lane = t & 63;
    float gc = g[lane], bc = b[lane];
    for (int row = blockIdx.x * 4 + wid; row < n; row += gridDim.x * 4) {
        float v = h[(size_t)row * 64 + lane];
        float s = v;
#pragma unroll
        for (int o = 32; o > 0; o >>= 1) s += __shfl_xor(s, o);
        float mu = s * (1.f / 64.f);
        float d = v - mu;
        float s2 = d * d;
#pragma unroll
        for (int o = 32; o > 0; o >>= 1) s2 += __shfl_xor(s2, o);
        float inv = rsqrtf(s2 * (1.f / 64.f) + LN_EPS);
        out[(size_t)row * 64 + lane] = fmaxf(d * inv * gc + bc, 0.f);
    }
}

// ---------------- edge MLP: wave-per-edge VALU ----------------
__global__ __launch_bounds__(256) void k_mlp_simple(
    const u16* __restrict__ hn, const u16* __restrict__ e_s,
    const int* __restrict__ dsts, const int* __restrict__ srcs,
    const u16* __restrict__ W1b, const float* __restrict__ b1,
    const float* __restrict__ W2f, const float* __restrict__ b2,
    const float* __restrict__ elng, const float* __restrict__ elnb,
    int ln_edge, u16* __restrict__ m_out, int E) {
    __shared__ u16 sW1[192 * 128];   // 48 KB
    int t = threadIdx.x;
    for (int i = t; i < 192 * 128; i += 256) sW1[i] = W1b[i];
    __syncthreads();

    int wid = t >> 6, lane = t & 63;
    float b1a = b1[lane];
    float b1b = b1[64 + lane];
    float b2c = b2[lane];
    float gln = ln_edge ? elng[lane] : 1.f;
    float bln = ln_edge ? elnb[lane] : 0.f;

    for (int pos = blockIdx.x * 4 + wid; pos < E; pos += gridDim.x * 4) {
        int dn = dsts[pos], sn = srcs[pos];
        float in0 = bf2f(hn[(size_t)dn * 64 + lane]);   // x_i = x[dst]
        float in1 = bf2f(hn[(size_t)sn * 64 + lane]);   // x_j = x[src]
        float ev  = bf2f(e_s[(size_t)pos * 64 + lane]);
        if (ln_edge) {
            float s = ev;
#pragma unroll
            for (int o = 32; o > 0; o >>= 1) s += __shfl_xor(s, o);
            float mu = s * (1.f / 64.f);
            float d = ev - mu;
            float s2 = d * d;
#pragma unroll
            for (int o = 32; o > 0; o >>= 1) s2 += __shfl_xor(s2, o);
            float inv = rsqrtf(s2 * (1.f / 64.f) + LN_EPS);
            ev = d * inv * gln + bln;
        }
        float acc0 = b1a, acc1 = b1b;
#pragma unroll
        for (int k = 0; k < 64; k++) {
            float f = __shfl(in0, k);
            acc0 += f * bf2f(sW1[k * 128 + lane]);
            acc1 += f * bf2f(sW1[k * 128 + 64 + lane]);
        }
#pragma unroll
        for (int k = 0; k < 64; k++) {
            float f = __shfl(in1, k);
            acc0 += f * bf2f(sW1[(64 + k) * 128 + lane]);
            acc1 += f * bf2f(sW1[(64 + k) * 128 + 64 + lane]);
        }
#pragma unroll
        for (int k = 0; k < 64; k++) {
            float f = __shfl(ev, k);
            acc0 += f * bf2f(sW1[(128 + k) * 128 + lane]);
            acc1 += f * bf2f(sW1[(128 + k) * 128 + 64 + lane]);
        }
        float h0 = fmaxf(acc0, 0.f);
        float h1 = fmaxf(acc1, 0.f);
        float acc2 = b2c;
#pragma unroll
        for (int k = 0; k < 64; k++)
            acc2 += __shfl(h0, k) * W2f[k * 64 + lane];
#pragma unroll
        for (int k = 0; k < 64; k++)
            acc2 += __shfl(h1, k) * W2f[(64 + k) * 64 + lane];
        m_out[(size_t)pos * 64 + lane] = f2bf(acc2);
    }
}

// ---------------- aggregation: online softmax over CSR + root weight ----------------
__global__ __launch_bounds__(256) void k_agg(
    const u16* __restrict__ m_s, u16* __restrict__ e_s,
    float* __restrict__ h, const u16* __restrict__ hn,
    const int* __restrict__ offs, const float* __restrict__ Wr,
    const float* __restrict__ tptr, int tidx,
    int add_h, int add_e, int write_e, int n, int E) {
    __shared__ float sWr[64 * 64];   // 16 KB
    int t = threadIdx.x;
    for (int i = t; i < 4096; i += 256) sWr[i] = Wr[i];
    __syncthreads();
    int wid = t >> 6, lane = t & 63;
    float tv = tptr[tidx];
    for (int node = blockIdx.x * 4 + wid; node < n; node += gridDim.x * 4) {
        int p0 = clampi(offs[node], 0, E);
        int p1 = clampi(offs[node + 1], p0, E);
        float M = -1e30f, D = 0.f, S = 0.f;
        for (int p = p0; p < p1; p++) {
            size_t ei = (size_t)p * 64 + lane;
            float mv = bf2f(m_s[ei]);
            if (write_e) {
                float evv = add_e ? bf2f(e_s[ei]) : 0.f;
                e_s[ei] = f2bf(evv + mv);
            }
            float lg = mv * tv;
            if (lg > M) {
                float r = __expf(M - lg);
                D = D * r + 1.f;
                S = S * r + mv;
                M = lg;
            } else {
                float p2 = __expf(lg - M);
                D += p2; S += mv * p2;
            }
        }
        float agg = (p1 > p0) ? (S / D) : 0.f;
        float hv = bf2f(hn[(size_t)node * 64 + lane]);
        float root = 0.f;
#pragma unroll
        for (int k = 0; k < 64; k++) {
            float xk = __shfl(hv, k);
            root += xk * sWr[k * 64 + lane];
        }
        size_t hi = (size_t)node * 64 + lane;
        float val = agg + root;
        h[hi] = add_h ? (h[hi] + val) : val;
    }
}

// ---------------- launcher ----------------
extern "C" void kernel_launch(void* const* d_in, const int* in_sizes, int n_in,
                              void* d_out, int out_size, void* d_ws, size_t ws_size,
                              hipStream_t stream) {
    float* outp = (float*)d_out;
    int FB = (out_size + 255) / 256;

    // Probe A: n_in mismatch -> 3.0 and stop.
    if (n_in != 17) {
        k_fill<<<FB, 256, 0, stream>>>(outp, out_size, 3.0f);
        return;
    }

    const float* x    = (const float*)d_in[0];
    const int*   ei   = (const int*)d_in[1];
    const float* ea   = (const float*)d_in[2];
    const float* nW   = (const float*)d_in[3];
    const float* nb   = (const float*)d_in[4];
    const float* eW   = (const float*)d_in[5];
    const float* eb   = (const float*)d_in[6];
    const float* cW1  = (const float*)d_in[7];
    const float* cb1  = (const float*)d_in[8];
    const float* cW2  = (const float*)d_in[9];
    const float* cb2  = (const float*)d_in[10];
    const float* cWr  = (const float*)d_in[11];
    const float* ct   = (const float*)d_in[12];
    const float* lng  = (const float*)d_in[13];
    const float* lnb  = (const float*)d_in[14];
    const float* elng = (const float*)d_in[15];
    const float* elnb = (const float*)d_in[16];

    const int n = in_sizes[0] / 128;   // 50000
    const int E = in_sizes[2] / 16;    // 500000

    char* ws = (char*)d_ws;
    size_t o = 0;
    auto alloc = [&](size_t bytes) -> void* {
        void* p = ws + o;
        o += (bytes + 255) & ~(size_t)255;
        return p;
    };
    int*   flag   = (int*)alloc(256);
    int*   deg    = (int*)alloc((size_t)n * 4);
    int*   offs   = (int*)alloc((size_t)(n + 1) * 4);
    int*   cursor = (int*)alloc((size_t)n * 4);
    int*   bsum   = (int*)alloc(256 * 4);
    int*   perm   = (int*)alloc((size_t)E * 4);
    int*   srcs   = (int*)alloc((size_t)E * 4);
    int*   dsts   = (int*)alloc((size_t)E * 4);
    float* h      = (float*)alloc((size_t)n * 64 * 4);
    u16*   hn     = (u16*)alloc((size_t)n * 64 * 2);
    u16*   e_s    = (u16*)alloc((size_t)E * 64 * 2);
    u16*   m_s    = (u16*)alloc((size_t)E * 64 * 2);
    u16*   W1b    = (u16*)alloc((size_t)3 * 24576 * 2);

    // Probe B: always pre-fill 1.0 (detects "pipeline died midway").
    k_fill<<<FB, 256, 0, stream>>>(outp, out_size, 1.0f);

    // Probe C: workspace too small -> 2.0 and stop.
    if (o > ws_size) {
        k_fill<<<FB, 256, 0, stream>>>(outp, out_size, 2.0f);
        return;
    }

    int SB = (n + 255) / 256;
    k_detect<<<1, 256, 0, stream>>>(ei, E, flag);
    k_zero<<<SB, 256, 0, stream>>>(deg, n);
    k_hist<<<(E + 255) / 256, 256, 0, stream>>>(ei, flag, deg, E, n);
    k_scan1<<<SB, 256, 0, stream>>>(deg, offs, bsum, n);
    k_scan2<<<1, 256, 0, stream>>>(bsum, SB);
    k_scan3<<<SB, 256, 0, stream>>>(offs, bsum, cursor, n, E);
    k_scatter<<<(E + 255) / 256, 256, 0, stream>>>(ei, flag, cursor, perm, srcs, dsts, E, n);
    k_wcvt<<<(3 * 24576 + 255) / 256, 256, 0, stream>>>(cW1, W1b, 3 * 24576);
    k_node_enc<<<1024, 256, 0, stream>>>(x, nW, nb, h, hn, n);
    k_edge_enc<<<2048, 256, 0, stream>>>(ea, perm, eW, eb, e_s, E);

    for (int i = 0; i < 3; i++) {
        if (i > 0)
            k_lnorm_bf<<<512, 256, 0, stream>>>(h, lng + (size_t)i * 64, lnb + (size_t)i * 64, hn, n);
        k_mlp_simple<<<2048, 256, 0, stream>>>(
            hn, e_s, dsts, srcs,
            W1b + (size_t)i * 24576, cb1 + (size_t)i * 128,
            cW2 + (size_t)i * 8192, cb2 + (size_t)i * 64,
            elng + (size_t)((i > 0) ? (i - 1) : 0) * 64,
            elnb + (size_t)((i > 0) ? (i - 1) : 0) * 64,
            (i > 0) ? 1 : 0, m_s, E);
        k_agg<<<1024, 256, 0, stream>>>(
            m_s, e_s, h, hn, offs, cWr + (size_t)i * 4096, ct, i,
            (i > 0) ? 1 : 0, (i > 0) ? 1 : 0, (i < 2) ? 1 : 0, n, E);
    }
    k_lnorm_out<<<512, 256, 0, stream>>>(h, lng, lnb, outp, n);
}

// Round 6
// 1389.676 us; speedup vs baseline: 20.3448x; 20.3448x over previous
//
#include <hip/hip_runtime.h>

typedef unsigned short u16;
typedef unsigned int u32;
typedef __attribute__((ext_vector_type(8))) short short8;
typedef __attribute__((ext_vector_type(4))) float floatx4;

#define LN_EPS 1e-5f

__device__ __forceinline__ float bf2f(u16 u) {
    union { u32 i; float f; } v; v.i = ((u32)u) << 16; return v.f;
}
__device__ __forceinline__ u16 f2bf(float f) {
    union { u32 i; float f; } v; v.f = f;
    u32 x = v.i;
    return (u16)((x + 0x7fffu + ((x >> 16) & 1u)) >> 16);
}
__device__ __forceinline__ int clampi(int v, int lo, int hi) {
    return v < lo ? lo : (v > hi ? hi : v);
}

// Diagnostic fill (f32).
__global__ void k_fill(float* __restrict__ out, int nel, float val) {
    int i = blockIdx.x * blockDim.x + threadIdx.x;
    if (i < nel) out[i] = val;
}

// ---------------- preprocessing ----------------
__global__ void k_zero(int* p, int n) {
    int i = blockIdx.x * blockDim.x + threadIdx.x;
    if (i < n) p[i] = 0;
}

__global__ void k_detect(const int* __restrict__ ei, int E, int* __restrict__ flag) {
    __shared__ int any;
    if (threadIdx.x == 0) any = 0;
    __syncthreads();
    int lim = (E < 4096) ? E : 4096;
    int v = 0;
    for (int i = threadIdx.x; i < lim; i += 256) v |= ei[2 * i + 1];
    if (v) atomicOr(&any, 1);
    __syncthreads();
    if (threadIdx.x == 0) flag[0] = (any == 0) ? 1 : 0;
}

__global__ void k_hist(const int* __restrict__ ei, const int* __restrict__ flag,
                       int* __restrict__ deg, int E, int n) {
    int e = blockIdx.x * blockDim.x + threadIdx.x;
    if (e < E) {
        int d = flag[0] ? ei[2 * ((size_t)E + e)] : ei[(size_t)E + e];
        atomicAdd(&deg[clampi(d, 0, n - 1)], 1);
    }
}

__global__ void k_scan1(const int* __restrict__ deg, int* __restrict__ offs,
                        int* __restrict__ bsum, int n) {
    __shared__ int s[256];
    int t = threadIdx.x;
    int i = blockIdx.x * 256 + t;
    int v = (i < n) ? deg[i] : 0;
    s[t] = v; __syncthreads();
    for (int off = 1; off < 256; off <<= 1) {
        int x = (t >= off) ? s[t - off] : 0;
        __syncthreads();
        s[t] += x;
        __syncthreads();
    }
    if (i < n) offs[i] = s[t] - v;
    if (t == 255) bsum[blockIdx.x] = s[255];
}

__global__ void k_scan2(int* bsum, int nb) {
    __shared__ int s[256];
    int t = threadIdx.x;
    int v = (t < nb) ? bsum[t] : 0;
    s[t] = v; __syncthreads();
    for (int off = 1; off < 256; off <<= 1) {
        int x = (t >= off) ? s[t - off] : 0;
        __syncthreads();
        s[t] += x;
        __syncthreads();
    }
    if (t < nb) bsum[t] = s[t] - v;
}

__global__ void k_scan3(int* __restrict__ offs, const int* __restrict__ bsum,
                        int* __restrict__ cursor, int n, int E) {
    int i = blockIdx.x * 256 + threadIdx.x;
    if (i < n) {
        int v = offs[i] + bsum[blockIdx.x];
        offs[i] = v;
        cursor[i] = v;
    }
    if (i == 0) offs[n] = E;
}

__global__ void k_scatter(const int* __restrict__ ei, const int* __restrict__ flag,
                          int* __restrict__ cursor,
                          int* __restrict__ perm, int* __restrict__ srcs,
                          int* __restrict__ dsts, int E, int n) {
    int e = blockIdx.x * blockDim.x + threadIdx.x;
    if (e < E) {
        int sv, dv;
        if (flag[0]) {
            sv = ei[2 * (size_t)e];
            dv = ei[2 * ((size_t)E + e)];
        } else {
            sv = ei[e];
            dv = ei[(size_t)E + e];
        }
        sv = clampi(sv, 0, n - 1);
        dv = clampi(dv, 0, n - 1);
        int p = clampi(atomicAdd(&cursor[dv], 1), 0, E - 1);
        perm[p] = e;
        srcs[p] = sv;
        dsts[p] = dv;
    }
}

// Pre-swizzle f32 weights into bf16 MFMA B-fragment order:
// B[k][n], k = kt*32 + q*8 + j  ->  idx = ((kt*4+q)*N + n)*8 + j
__global__ void k_swz(const float* __restrict__ W1, const float* __restrict__ W2,
                      u16* __restrict__ W1s, u16* __restrict__ W2s) {
    int i = blockIdx.x * blockDim.x + threadIdx.x;
    if (i < 3 * 24576) {
        int l = i / 24576, rem = i % 24576;
        int k = rem / 128, n = rem % 128;
        int kt = k >> 5, q = (k >> 3) & 3, j = k & 7;
        W1s[l * 24576 + ((kt * 4 + q) * 128 + n) * 8 + j] = f2bf(W1[i]);
    }
    if (i < 3 * 8192) {
        int l = i / 8192, rem = i % 8192;
        int k = rem / 64, n = rem % 64;
        int kt = k >> 5, q = (k >> 3) & 3, j = k & 7;
        W2s[l * 8192 + ((kt * 4 + q) * 64 + n) * 8 + j] = f2bf(W2[i]);
    }
}

// ---------------- encoders (f32 inputs) ----------------
__global__ __launch_bounds__(256) void k_node_enc(
    const float* __restrict__ x, const float* __restrict__ W, const float* __restrict__ bias,
    float* __restrict__ h, u16* __restrict__ hn, int n) {
    __shared__ float sW[128 * 64];   // 32 KB
    int t = threadIdx.x;
    for (int i = t; i < 128 * 64; i += 256) sW[i] = W[i];
    __syncthreads();
    int wid = t >> 6, lane = t & 63;
    float bc = bias[lane];
    for (int row = blockIdx.x * 4 + wid; row < n; row += gridDim.x * 4) {
        float2 pr = ((const float2*)(x + (size_t)row * 128))[lane];
        float acc = bc;
#pragma unroll
        for (int k = 0; k < 128; k++) {
            float f = __shfl((k & 1) ? pr.y : pr.x, k >> 1);
            acc += f * sW[k * 64 + lane];
        }
        h[(size_t)row * 64 + lane] = acc;
        hn[(size_t)row * 64 + lane] = f2bf(acc);
    }
}

__global__ __launch_bounds__(256) void k_edge_enc(
    const float* __restrict__ ea, const int* __restrict__ perm,
    const float* __restrict__ W, const float* __restrict__ bias,
    u16* __restrict__ e_s, int E) {
    __shared__ float sW[16 * 64];    // 4 KB
    int t = threadIdx.x;
    for (int i = t; i < 16 * 64; i += 256) sW[i] = W[i];
    __syncthreads();
    int wid = t >> 6, lane = t & 63;
    float bc = bias[lane];
    for (int pos = blockIdx.x * 4 + wid; pos < E; pos += gridDim.x * 4) {
        int e = perm[pos];
        float pr = (lane < 16) ? ea[(size_t)e * 16 + lane] : 0.f;
        float acc = bc;
#pragma unroll
        for (int k = 0; k < 16; k++) {
            float f = __shfl(pr, k);
            acc += f * sW[k * 64 + lane];
        }
        e_s[(size_t)pos * 64 + lane] = f2bf(acc);
    }
}

// ---------------- layernorm: bf16-out (hn producer) and f32-out (final) ----------------
__global__ __launch_bounds__(256) void k_lnorm_bf(
    const float* __restrict__ h, const float* __restrict__ g, const float* __restrict__ b,
    u16* __restrict__ out, int n) {
    int t = threadIdx.x, wid = t >> 6, lane = t & 63;
    float gc = g[lane], bc = b[lane];
    for (int row = blockIdx.x * 4 + wid; row < n; row += gridDim.x * 4) {
        float v = h[(size_t)row * 64 + lane];
        float s = v;
#pragma unroll
        for (int o = 32; o > 0; o >>= 1) s += __shfl_xor(s, o);
        float mu = s * (1.f / 64.f);
        float d = v - mu;
        float s2 = d * d;
#pragma unroll
        for (int o = 32; o > 0; o >>= 1) s2 += __shfl_xor(s2, o);
        float inv = rsqrtf(s2 * (1.f / 64.f) + LN_EPS);
        float r = fmaxf(d * inv * gc + bc, 0.f);
        out[(size_t)row * 64 + lane] = f2bf(r);
    }
}

__global__ __launch_bounds__(256) void k_lnorm_out(
    const float* __restrict__ h, const float* __restrict__ g, const float* __restrict__ b,
    float* __restrict__ out, int n) {
    int t = threadIdx.x, wid = t >> 6, lane = t & 63;
    float gc = g[lane], bc = b[lane];
    for (int row = blockIdx.x * 4 + wid; row < n; row += gridDim.x * 4) {
        float v = h[(size_t)row * 64 + lane];
        float s = v;
#pragma unroll
        for (int o = 32; o > 0; o >>= 1) s += __shfl_xor(s, o);
        float mu = s * (1.f / 64.f);
        float d = v - mu;
        float s2 = d * d;
#pragma unroll
        for (int o = 32; o > 0; o >>= 1) s2 += __shfl_xor(s2, o);
        float inv = rsqrtf(s2 * (1.f / 64.f) + LN_EPS);
        out[(size_t)row * 64 + lane] = fmaxf(d * inv * gc + bc, 0.f);
    }
}

// ---------------- edge MLP (MFMA) ----------------
// Tile = 128 edges, 512 threads (8 waves). Per-wave LDS arena: 16 edge-rows in
// MFMA A-frag order (24 chunks x 128 shorts); hidden acts alias the same arena.
#define TILE 128
__global__ __launch_bounds__(512) void k_mlp(
    const u16* __restrict__ hn, const u16* __restrict__ e_s,
    const int* __restrict__ dsts, const int* __restrict__ srcs,
    const u16* __restrict__ W1s, const float* __restrict__ b1,
    const u16* __restrict__ W2s, const float* __restrict__ b2,
    const float* __restrict__ elng, const float* __restrict__ elnb,
    int ln_edge, u16* __restrict__ m_out, int E) {
    __shared__ short sA[8 * 3072];       // 48 KB
    __shared__ float sSum[TILE][4];
    __shared__ float sSq[TILE][4];
    __shared__ float sMu[TILE], sInv[TILE];

    int t = threadIdx.x;
    int base = blockIdx.x * TILE;

    // ---- staging: gather hn[dst], hn[src], LN(e) into swizzled A-layout ----
    {
        int r = t >> 2, s = t & 3;       // row 0..127, quarter 0..3 (16 cols)
        int pos = base + r;
        int g = r >> 4, m = r & 15;
        short* grp = sA + g * 3072;
        bool act = pos < E;
        int dn = 0, sn = 0;
        if (act) { dn = dsts[pos]; sn = srcs[pos]; }
        uint4 z4 = make_uint4(0, 0, 0, 0);
        const uint4* pd = (const uint4*)(hn + (size_t)dn * 64);
        const uint4* ps = (const uint4*)(hn + (size_t)sn * 64);
        uint4 d0 = act ? pd[2 * s] : z4;
        uint4 d1 = act ? pd[2 * s + 1] : z4;
        uint4 s0 = act ? ps[2 * s] : z4;
        uint4 s1 = act ? ps[2 * s + 1] : z4;
        int ch = (s >> 1) * 4 + (s & 1) * 2;                 // dst segment
        *((uint4*)(grp + ch * 128 + m * 8)) = d0;
        *((uint4*)(grp + (ch + 1) * 128 + m * 8)) = d1;
        int ch2 = (2 + (s >> 1)) * 4 + (s & 1) * 2;          // src segment
        *((uint4*)(grp + ch2 * 128 + m * 8)) = s0;
        *((uint4*)(grp + (ch2 + 1) * 128 + m * 8)) = s1;

        const u32* pe = (const u32*)(e_s + (size_t)pos * 64) + s * 8;
        float ev[16];
        float sm = 0.f, sq = 0.f;
#pragma unroll
        for (int i2 = 0; i2 < 8; i2++) {
            u32 u = act ? pe[i2] : 0u;
            float f0 = bf2f((u16)(u & 0xffffu));
            float f1 = bf2f((u16)(u >> 16));
            ev[2 * i2] = f0; ev[2 * i2 + 1] = f1;
            sm += f0 + f1; sq += f0 * f0 + f1 * f1;
        }
        sSum[r][s] = sm; sSq[r][s] = sq;
        __syncthreads();
        if (t < TILE) {
            float S = sSum[t][0] + sSum[t][1] + sSum[t][2] + sSum[t][3];
            float Q = sSq[t][0] + sSq[t][1] + sSq[t][2] + sSq[t][3];
            float mu = S * (1.f / 64.f);
            float var = Q * (1.f / 64.f) - mu * mu;
            sMu[t] = mu; sInv[t] = rsqrtf(fmaxf(var, 0.f) + LN_EPS);
        }
        __syncthreads();
        float mu = ln_edge ? sMu[r] : 0.f;
        float inv = ln_edge ? sInv[r] : 1.f;
        int ch3 = (4 + (s >> 1)) * 4 + (s & 1) * 2;          // e segment
        u16* wp0 = (u16*)(grp + ch3 * 128 + m * 8);
        u16* wp1 = (u16*)(grp + (ch3 + 1) * 128 + m * 8);
#pragma unroll
        for (int i2 = 0; i2 < 16; i2++) {
            float v = ev[i2];
            if (ln_edge) {
                int c = s * 16 + i2;
                v = (v - mu) * inv * elng[c] + elnb[c];
            }
            ((i2 < 8) ? wp0 : wp1)[i2 & 7] = f2bf(v);
        }
    }
    __syncthreads();

    // ---- GEMM1: [16 x 192] @ W1[192,128] per wave ----
    int w = t >> 6, l = t & 63, q = l >> 4, ml = l & 15;
    short* arena = sA + w * 3072;
    float b1c[8], b2c[4];
#pragma unroll
    for (int nt = 0; nt < 8; nt++) b1c[nt] = b1[nt * 16 + ml];
#pragma unroll
    for (int nt = 0; nt < 4; nt++) b2c[nt] = b2[nt * 16 + ml];

    floatx4 acc[8];
#pragma unroll
    for (int nt = 0; nt < 8; nt++) acc[nt] = floatx4{0.f, 0.f, 0.f, 0.f};
#pragma unroll
    for (int kt = 0; kt < 6; kt++) {
        short8 a = *((const short8*)(arena + (kt * 4 + q) * 128 + ml * 8));
#pragma unroll
        for (int nt = 0; nt < 8; nt++) {
            short8 bf = *((const short8*)(W1s + (size_t)((kt * 4 + q) * 128 + nt * 16 + ml) * 8));
            acc[nt] = __builtin_amdgcn_mfma_f32_16x16x32_bf16(a, bf, acc[nt], 0, 0, 0);
        }
    }
    // relu + bias, repack hidden (bf16) into arena in A-frag order (wave-private)
#pragma unroll
    for (int nt = 0; nt < 8; nt++) {
#pragma unroll
        for (int r2 = 0; r2 < 4; r2++) {
            float v = fmaxf(acc[nt][r2] + b1c[nt], 0.f);
            int m2 = q * 4 + r2;
            int c2 = nt * 16 + ml;
            int kt2 = c2 >> 5, qq = (c2 >> 3) & 3, j = c2 & 7;
            ((u16*)arena)[(kt2 * 4 + qq) * 128 + m2 * 8 + j] = f2bf(v);
        }
    }
    // ---- GEMM2: [16 x 128] @ W2[128,64] ----
    floatx4 acc2[4];
#pragma unroll
    for (int nt = 0; nt < 4; nt++) acc2[nt] = floatx4{0.f, 0.f, 0.f, 0.f};
#pragma unroll
    for (int kt = 0; kt < 4; kt++) {
        short8 a = *((const short8*)(arena + (kt * 4 + q) * 128 + ml * 8));
#pragma unroll
        for (int nt = 0; nt < 4; nt++) {
            short8 bf = *((const short8*)(W2s + (size_t)((kt * 4 + q) * 64 + nt * 16 + ml) * 8));
            acc2[nt] = __builtin_amdgcn_mfma_f32_16x16x32_bf16(a, bf, acc2[nt], 0, 0, 0);
        }
    }
#pragma unroll
    for (int nt = 0; nt < 4; nt++) {
#pragma unroll
        for (int r2 = 0; r2 < 4; r2++) {
            int row = w * 16 + q * 4 + r2;
            int pos = base + row;
            if (pos < E)
                m_out[(size_t)pos * 64 + nt * 16 + ml] = f2bf(acc2[nt][r2] + b2c[nt]);
        }
    }
}

// ---------------- aggregation: online softmax over CSR + root weight ----------------
__global__ __launch_bounds__(256) void k_agg(
    const u16* __restrict__ m_s, u16* __restrict__ e_s,
    float* __restrict__ h, const u16* __restrict__ hn,
    const int* __restrict__ offs, const float* __restrict__ Wr,
    const float* __restrict__ tptr, int tidx,
    int add_h, int add_e, int write_e, int n, int E) {
    __shared__ float sWr[64 * 64];   // 16 KB
    int t = threadIdx.x;
    for (int i = t; i < 4096; i += 256) sWr[i] = Wr[i];
    __syncthreads();
    int wid = t >> 6, lane = t & 63;
    float tv = tptr[tidx];
    for (int node = blockIdx.x * 4 + wid; node < n; node += gridDim.x * 4) {
        int p0 = clampi(offs[node], 0, E);
        int p1 = clampi(offs[node + 1], p0, E);
        float M = -1e30f, D = 0.f, S = 0.f;
        for (int p = p0; p < p1; p++) {
            size_t ei = (size_t)p * 64 + lane;
            float mv = bf2f(m_s[ei]);
            if (write_e) {
                float evv = add_e ? bf2f(e_s[ei]) : 0.f;
                e_s[ei] = f2bf(evv + mv);
            }
            float lg = mv * tv;
            if (lg > M) {
                float r = __expf(M - lg);
                D = D * r + 1.f;
                S = S * r + mv;
                M = lg;
            } else {
                float p2 = __expf(lg - M);
                D += p2; S += mv * p2;
            }
        }
        float agg = (p1 > p0) ? (S / D) : 0.f;
        float hv = bf2f(hn[(size_t)node * 64 + lane]);
        float root = 0.f;
#pragma unroll
        for (int k = 0; k < 64; k++) {
            float xk = __shfl(hv, k);
            root += xk * sWr[k * 64 + lane];
        }
        size_t hi = (size_t)node * 64 + lane;
        float val = agg + root;
        h[hi] = add_h ? (h[hi] + val) : val;
    }
}

// ---------------- launcher ----------------
extern "C" void kernel_launch(void* const* d_in, const int* in_sizes, int n_in,
                              void* d_out, int out_size, void* d_ws, size_t ws_size,
                              hipStream_t stream) {
    float* outp = (float*)d_out;
    int FB = (out_size + 255) / 256;

    if (n_in != 17) {
        k_fill<<<FB, 256, 0, stream>>>(outp, out_size, 3.0f);
        return;
    }

    const float* x    = (const float*)d_in[0];
    const int*   ei   = (const int*)d_in[1];
    const float* ea   = (const float*)d_in[2];
    const float* nW   = (const float*)d_in[3];
    const float* nb   = (const float*)d_in[4];
    const float* eW   = (const float*)d_in[5];
    const float* eb   = (const float*)d_in[6];
    const float* cW1  = (const float*)d_in[7];
    const float* cb1  = (const float*)d_in[8];
    const float* cW2  = (const float*)d_in[9];
    const float* cb2  = (const float*)d_in[10];
    const float* cWr  = (const float*)d_in[11];
    const float* ct   = (const float*)d_in[12];
    const float* lng  = (const float*)d_in[13];
    const float* lnb  = (const float*)d_in[14];
    const float* elng = (const float*)d_in[15];
    const float* elnb = (const float*)d_in[16];

    const int n = in_sizes[0] / 128;   // 50000
    const int E = in_sizes[2] / 16;    // 500000

    char* ws = (char*)d_ws;
    size_t o = 0;
    auto alloc = [&](size_t bytes) -> void* {
        void* p = ws + o;
        o += (bytes + 255) & ~(size_t)255;
        return p;
    };
    int*   flag   = (int*)alloc(256);
    int*   deg    = (int*)alloc((size_t)n * 4);
    int*   offs   = (int*)alloc((size_t)(n + 1) * 4);
    int*   cursor = (int*)alloc((size_t)n * 4);
    int*   bsum   = (int*)alloc(256 * 4);
    int*   perm   = (int*)alloc((size_t)E * 4);
    int*   srcs   = (int*)alloc((size_t)E * 4);
    int*   dsts   = (int*)alloc((size_t)E * 4);
    float* h      = (float*)alloc((size_t)n * 64 * 4);
    u16*   hn     = (u16*)alloc((size_t)n * 64 * 2);
    u16*   e_s    = (u16*)alloc((size_t)E * 64 * 2);
    u16*   m_s    = (u16*)alloc((size_t)E * 64 * 2);
    u16*   W1s    = (u16*)alloc((size_t)3 * 24576 * 2);
    u16*   W2s    = (u16*)alloc((size_t)3 * 8192 * 2);

    k_fill<<<FB, 256, 0, stream>>>(outp, out_size, 1.0f);
    if (o > ws_size) {
        k_fill<<<FB, 256, 0, stream>>>(outp, out_size, 2.0f);
        return;
    }

    int SB = (n + 255) / 256;
    k_detect<<<1, 256, 0, stream>>>(ei, E, flag);
    k_zero<<<SB, 256, 0, stream>>>(deg, n);
    k_hist<<<(E + 255) / 256, 256, 0, stream>>>(ei, flag, deg, E, n);
    k_scan1<<<SB, 256, 0, stream>>>(deg, offs, bsum, n);
    k_scan2<<<1, 256, 0, stream>>>(bsum, SB);
    k_scan3<<<SB, 256, 0, stream>>>(offs, bsum, cursor, n, E);
    k_scatter<<<(E + 255) / 256, 256, 0, stream>>>(ei, flag, cursor, perm, srcs, dsts, E, n);
    k_swz<<<(3 * 24576 + 255) / 256, 256, 0, stream>>>(cW1, cW2, W1s, W2s);
    k_node_enc<<<1024, 256, 0, stream>>>(x, nW, nb, h, hn, n);
    k_edge_enc<<<2048, 256, 0, stream>>>(ea, perm, eW, eb, e_s, E);

    int MB = (E + TILE - 1) / TILE;
    for (int i = 0; i < 3; i++) {
        if (i > 0)
            k_lnorm_bf<<<512, 256, 0, stream>>>(h, lng + (size_t)i * 64, lnb + (size_t)i * 64, hn, n);
        k_mlp<<<MB, 512, 0, stream>>>(
            hn, e_s, dsts, srcs,
            W1s + (size_t)i * 24576, cb1 + (size_t)i * 128,
            W2s + (size_t)i * 8192, cb2 + (size_t)i * 64,
            elng + (size_t)((i > 0) ? (i - 1) : 0) * 64,
            elnb + (size_t)((i > 0) ? (i - 1) : 0) * 64,
            (i > 0) ? 1 : 0, m_s, E);
        k_agg<<<1024, 256, 0, stream>>>(
            m_s, e_s, h, hn, offs, cWr + (size_t)i * 4096, ct, i,
            (i > 0) ? 1 : 0, (i > 0) ? 1 : 0, (i < 2) ? 1 : 0, n, E);
    }
    k_lnorm_out<<<512, 256, 0, stream>>>(h, lng, lnb, outp, n);
}

// Round 7
// 973.448 us; speedup vs baseline: 29.0439x; 1.4276x over previous
//
#include <hip/hip_runtime.h>

typedef unsigned short u16;
typedef unsigned int u32;
typedef __attribute__((ext_vector_type(8))) short short8;
typedef __attribute__((ext_vector_type(4))) float floatx4;

#define LN_EPS 1e-5f

__device__ __forceinline__ float bf2f(u16 u) {
    union { u32 i; float f; } v; v.i = ((u32)u) << 16; return v.f;
}
__device__ __forceinline__ u16 f2bf(float f) {
    union { u32 i; float f; } v; v.f = f;
    u32 x = v.i;
    return (u16)((x + 0x7fffu + ((x >> 16) & 1u)) >> 16);
}
__device__ __forceinline__ int clampi(int v, int lo, int hi) {
    return v < lo ? lo : (v > hi ? hi : v);
}

// Diagnostic fill (f32).
__global__ void k_fill(float* __restrict__ out, int nel, float val) {
    int i = blockIdx.x * blockDim.x + threadIdx.x;
    if (i < nel) out[i] = val;
}

// ---------------- preprocessing ----------------
__global__ void k_zero(int* p, int n) {
    int i = blockIdx.x * blockDim.x + threadIdx.x;
    if (i < n) p[i] = 0;
}

__global__ void k_detect(const int* __restrict__ ei, int E, int* __restrict__ flag) {
    __shared__ int any;
    if (threadIdx.x == 0) any = 0;
    __syncthreads();
    int lim = (E < 4096) ? E : 4096;
    int v = 0;
    for (int i = threadIdx.x; i < lim; i += 256) v |= ei[2 * i + 1];
    if (v) atomicOr(&any, 1);
    __syncthreads();
    if (threadIdx.x == 0) flag[0] = (any == 0) ? 1 : 0;
}

__global__ void k_hist(const int* __restrict__ ei, const int* __restrict__ flag,
                       int* __restrict__ deg, int E, int n) {
    int e = blockIdx.x * blockDim.x + threadIdx.x;
    if (e < E) {
        int d = flag[0] ? ei[2 * ((size_t)E + e)] : ei[(size_t)E + e];
        atomicAdd(&deg[clampi(d, 0, n - 1)], 1);
    }
}

__global__ void k_scan1(const int* __restrict__ deg, int* __restrict__ offs,
                        int* __restrict__ bsum, int n) {
    __shared__ int s[256];
    int t = threadIdx.x;
    int i = blockIdx.x * 256 + t;
    int v = (i < n) ? deg[i] : 0;
    s[t] = v; __syncthreads();
    for (int off = 1; off < 256; off <<= 1) {
        int x = (t >= off) ? s[t - off] : 0;
        __syncthreads();
        s[t] += x;
        __syncthreads();
    }
    if (i < n) offs[i] = s[t] - v;
    if (t == 255) bsum[blockIdx.x] = s[255];
}

__global__ void k_scan2(int* bsum, int nb) {
    __shared__ int s[256];
    int t = threadIdx.x;
    int v = (t < nb) ? bsum[t] : 0;
    s[t] = v; __syncthreads();
    for (int off = 1; off < 256; off <<= 1) {
        int x = (t >= off) ? s[t - off] : 0;
        __syncthreads();
        s[t] += x;
        __syncthreads();
    }
    if (t < nb) bsum[t] = s[t] - v;
}

__global__ void k_scan3(int* __restrict__ offs, const int* __restrict__ bsum,
                        int* __restrict__ cursor, int n, int E) {
    int i = blockIdx.x * 256 + threadIdx.x;
    if (i < n) {
        int v = offs[i] + bsum[blockIdx.x];
        offs[i] = v;
        cursor[i] = v;
    }
    if (i == 0) offs[n] = E;
}

__global__ void k_scatter(const int* __restrict__ ei, const int* __restrict__ flag,
                          int* __restrict__ cursor,
                          int* __restrict__ perm, int* __restrict__ srcs,
                          int* __restrict__ dsts, int E, int n) {
    int e = blockIdx.x * blockDim.x + threadIdx.x;
    if (e < E) {
        int sv, dv;
        if (flag[0]) {
            sv = ei[2 * (size_t)e];
            dv = ei[2 * ((size_t)E + e)];
        } else {
            sv = ei[e];
            dv = ei[(size_t)E + e];
        }
        sv = clampi(sv, 0, n - 1);
        dv = clampi(dv, 0, n - 1);
        int p = clampi(atomicAdd(&cursor[dv], 1), 0, E - 1);
        perm[p] = e;
        srcs[p] = sv;
        dsts[p] = dv;
    }
}

// Pre-swizzle f32 weights into bf16 MFMA B-fragment order:
// B[k][n], k = kt*32 + q*8 + j  ->  idx = ((kt*4+q)*N + n)*8 + j
__global__ void k_swz(const float* __restrict__ W1, const float* __restrict__ W2,
                      const float* __restrict__ Wr,
                      u16* __restrict__ W1s, u16* __restrict__ W2s,
                      u16* __restrict__ Wrs) {
    int i = blockIdx.x * blockDim.x + threadIdx.x;
    if (i < 3 * 24576) {
        int l = i / 24576, rem = i % 24576;
        int k = rem / 128, n = rem % 128;
        int kt = k >> 5, q = (k >> 3) & 3, j = k & 7;
        W1s[l * 24576 + ((kt * 4 + q) * 128 + n) * 8 + j] = f2bf(W1[i]);
    }
    if (i < 3 * 8192) {
        int l = i / 8192, rem = i % 8192;
        int k = rem / 64, n = rem % 64;
        int kt = k >> 5, q = (k >> 3) & 3, j = k & 7;
        W2s[l * 8192 + ((kt * 4 + q) * 64 + n) * 8 + j] = f2bf(W2[i]);
    }
    if (i < 3 * 4096) {
        int l = i / 4096, rem = i % 4096;
        int k = rem / 64, n = rem % 64;
        int kt = k >> 5, q = (k >> 3) & 3, j = k & 7;
        Wrs[l * 4096 + ((kt * 4 + q) * 64 + n) * 8 + j] = f2bf(Wr[i]);
    }
}

// ---------------- encoders (f32 inputs) ----------------
__global__ __launch_bounds__(256) void k_node_enc(
    const float* __restrict__ x, const float* __restrict__ W, const float* __restrict__ bias,
    float* __restrict__ h, u16* __restrict__ hn, int n) {
    __shared__ float sW[128 * 64];   // 32 KB
    int t = threadIdx.x;
    for (int i = t; i < 128 * 64; i += 256) sW[i] = W[i];
    __syncthreads();
    int wid = t >> 6, lane = t & 63;
    float bc = bias[lane];
    for (int row = blockIdx.x * 4 + wid; row < n; row += gridDim.x * 4) {
        float2 pr = ((const float2*)(x + (size_t)row * 128))[lane];
        float acc = bc;
#pragma unroll
        for (int k = 0; k < 128; k++) {
            float f = __shfl((k & 1) ? pr.y : pr.x, k >> 1);
            acc += f * sW[k * 64 + lane];
        }
        h[(size_t)row * 64 + lane] = acc;
        hn[(size_t)row * 64 + lane] = f2bf(acc);
    }
}

__global__ __launch_bounds__(256) void k_edge_enc(
    const float* __restrict__ ea, const int* __restrict__ perm,
    const float* __restrict__ W, const float* __restrict__ bias,
    u16* __restrict__ e_s, int E) {
    __shared__ float sW[16 * 64];    // 4 KB
    int t = threadIdx.x;
    for (int i = t; i < 16 * 64; i += 256) sW[i] = W[i];
    __syncthreads();
    int wid = t >> 6, lane = t & 63;
    float bc = bias[lane];
    for (int pos = blockIdx.x * 4 + wid; pos < E; pos += gridDim.x * 4) {
        int e = perm[pos];
        float pr = (lane < 16) ? ea[(size_t)e * 16 + lane] : 0.f;
        float acc = bc;
#pragma unroll
        for (int k = 0; k < 16; k++) {
            float f = __shfl(pr, k);
            acc += f * sW[k * 64 + lane];
        }
        e_s[(size_t)pos * 64 + lane] = f2bf(acc);
    }
}

// ---------------- layernorm: bf16-out (hn producer) and f32-out (final) ----------------
__global__ __launch_bounds__(256) void k_lnorm_bf(
    const float* __restrict__ h, const float* __restrict__ g, const float* __restrict__ b,
    u16* __restrict__ out, int n) {
    int t = threadIdx.x, wid = t >> 6, lane = t & 63;
    float gc = g[lane], bc = b[lane];
    for (int row = blockIdx.x * 4 + wid; row < n; row += gridDim.x * 4) {
        float v = h[(size_t)row * 64 + lane];
        float s = v;
#pragma unroll
        for (int o = 32; o > 0; o >>= 1) s += __shfl_xor(s, o);
        float mu = s * (1.f / 64.f);
        float d = v - mu;
        float s2 = d * d;
#pragma unroll
        for (int o = 32; o > 0; o >>= 1) s2 += __shfl_xor(s2, o);
        float inv = rsqrtf(s2 * (1.f / 64.f) + LN_EPS);
        float r = fmaxf(d * inv * gc + bc, 0.f);
        out[(size_t)row * 64 + lane] = f2bf(r);
    }
}

__global__ __launch_bounds__(256) void k_lnorm_out(
    const float* __restrict__ h, const float* __restrict__ g, const float* __restrict__ b,
    float* __restrict__ out, int n) {
    int t = threadIdx.x, wid = t >> 6, lane = t & 63;
    float gc = g[lane], bc = b[lane];
    for (int row = blockIdx.x * 4 + wid; row < n; row += gridDim.x * 4) {
        float v = h[(size_t)row * 64 + lane];
        float s = v;
#pragma unroll
        for (int o = 32; o > 0; o >>= 1) s += __shfl_xor(s, o);
        float mu = s * (1.f / 64.f);
        float d = v - mu;
        float s2 = d * d;
#pragma unroll
        for (int o = 32; o > 0; o >>= 1) s2 += __shfl_xor(s2, o);
        float inv = rsqrtf(s2 * (1.f / 64.f) + LN_EPS);
        out[(size_t)row * 64 + lane] = fmaxf(d * inv * gc + bc, 0.f);
    }
}

// ---------------- edge MLP (MFMA) ----------------
#define TILE 128
__global__ __launch_bounds__(512) void k_mlp(
    const u16* __restrict__ hn, const u16* __restrict__ e_s,
    const int* __restrict__ dsts, const int* __restrict__ srcs,
    const u16* __restrict__ W1s, const float* __restrict__ b1,
    const u16* __restrict__ W2s, const float* __restrict__ b2,
    const float* __restrict__ elng, const float* __restrict__ elnb,
    int ln_edge, u16* __restrict__ m_out, int E) {
    __shared__ short sA[8 * 3072];       // 48 KB
    __shared__ float sSum[TILE][4];
    __shared__ float sSq[TILE][4];
    __shared__ float sMu[TILE], sInv[TILE];

    int t = threadIdx.x;
    int base = blockIdx.x * TILE;

    {
        int r = t >> 2, s = t & 3;
        int pos = base + r;
        int g = r >> 4, m = r & 15;
        short* grp = sA + g * 3072;
        bool act = pos < E;
        int dn = 0, sn = 0;
        if (act) { dn = dsts[pos]; sn = srcs[pos]; }
        uint4 z4 = make_uint4(0, 0, 0, 0);
        const uint4* pd = (const uint4*)(hn + (size_t)dn * 64);
        const uint4* ps = (const uint4*)(hn + (size_t)sn * 64);
        uint4 d0 = act ? pd[2 * s] : z4;
        uint4 d1 = act ? pd[2 * s + 1] : z4;
        uint4 s0 = act ? ps[2 * s] : z4;
        uint4 s1 = act ? ps[2 * s + 1] : z4;
        int ch = (s >> 1) * 4 + (s & 1) * 2;
        *((uint4*)(grp + ch * 128 + m * 8)) = d0;
        *((uint4*)(grp + (ch + 1) * 128 + m * 8)) = d1;
        int ch2 = (2 + (s >> 1)) * 4 + (s & 1) * 2;
        *((uint4*)(grp + ch2 * 128 + m * 8)) = s0;
        *((uint4*)(grp + (ch2 + 1) * 128 + m * 8)) = s1;

        const u32* pe = (const u32*)(e_s + (size_t)pos * 64) + s * 8;
        float ev[16];
        float sm = 0.f, sq = 0.f;
#pragma unroll
        for (int i2 = 0; i2 < 8; i2++) {
            u32 u = act ? pe[i2] : 0u;
            float f0 = bf2f((u16)(u & 0xffffu));
            float f1 = bf2f((u16)(u >> 16));
            ev[2 * i2] = f0; ev[2 * i2 + 1] = f1;
            sm += f0 + f1; sq += f0 * f0 + f1 * f1;
        }
        sSum[r][s] = sm; sSq[r][s] = sq;
        __syncthreads();
        if (t < TILE) {
            float S = sSum[t][0] + sSum[t][1] + sSum[t][2] + sSum[t][3];
            float Q = sSq[t][0] + sSq[t][1] + sSq[t][2] + sSq[t][3];
            float mu = S * (1.f / 64.f);
            float var = Q * (1.f / 64.f) - mu * mu;
            sMu[t] = mu; sInv[t] = rsqrtf(fmaxf(var, 0.f) + LN_EPS);
        }
        __syncthreads();
        float mu = ln_edge ? sMu[r] : 0.f;
        float inv = ln_edge ? sInv[r] : 1.f;
        int ch3 = (4 + (s >> 1)) * 4 + (s & 1) * 2;
        u16* wp0 = (u16*)(grp + ch3 * 128 + m * 8);
        u16* wp1 = (u16*)(grp + (ch3 + 1) * 128 + m * 8);
#pragma unroll
        for (int i2 = 0; i2 < 16; i2++) {
            float v = ev[i2];
            if (ln_edge) {
                int c = s * 16 + i2;
                v = (v - mu) * inv * elng[c] + elnb[c];
            }
            ((i2 < 8) ? wp0 : wp1)[i2 & 7] = f2bf(v);
        }
    }
    __syncthreads();

    int w = t >> 6, l = t & 63, q = l >> 4, ml = l & 15;
    short* arena = sA + w * 3072;
    float b1c[8], b2c[4];
#pragma unroll
    for (int nt = 0; nt < 8; nt++) b1c[nt] = b1[nt * 16 + ml];
#pragma unroll
    for (int nt = 0; nt < 4; nt++) b2c[nt] = b2[nt * 16 + ml];

    floatx4 acc[8];
#pragma unroll
    for (int nt = 0; nt < 8; nt++) acc[nt] = floatx4{0.f, 0.f, 0.f, 0.f};
#pragma unroll
    for (int kt = 0; kt < 6; kt++) {
        short8 a = *((const short8*)(arena + (kt * 4 + q) * 128 + ml * 8));
#pragma unroll
        for (int nt = 0; nt < 8; nt++) {
            short8 bf = *((const short8*)(W1s + (size_t)((kt * 4 + q) * 128 + nt * 16 + ml) * 8));
            acc[nt] = __builtin_amdgcn_mfma_f32_16x16x32_bf16(a, bf, acc[nt], 0, 0, 0);
        }
    }
#pragma unroll
    for (int nt = 0; nt < 8; nt++) {
#pragma unroll
        for (int r2 = 0; r2 < 4; r2++) {
            float v = fmaxf(acc[nt][r2] + b1c[nt], 0.f);
            int m2 = q * 4 + r2;
            int c2 = nt * 16 + ml;
            int kt2 = c2 >> 5, qq = (c2 >> 3) & 3, j = c2 & 7;
            ((u16*)arena)[(kt2 * 4 + qq) * 128 + m2 * 8 + j] = f2bf(v);
        }
    }
    floatx4 acc2[4];
#pragma unroll
    for (int nt = 0; nt < 4; nt++) acc2[nt] = floatx4{0.f, 0.f, 0.f, 0.f};
#pragma unroll
    for (int kt = 0; kt < 4; kt++) {
        short8 a = *((const short8*)(arena + (kt * 4 + q) * 128 + ml * 8));
#pragma unroll
        for (int nt = 0; nt < 4; nt++) {
            short8 bf = *((const short8*)(W2s + (size_t)((kt * 4 + q) * 64 + nt * 16 + ml) * 8));
            acc2[nt] = __builtin_amdgcn_mfma_f32_16x16x32_bf16(a, bf, acc2[nt], 0, 0, 0);
        }
    }
#pragma unroll
    for (int nt = 0; nt < 4; nt++) {
#pragma unroll
        for (int r2 = 0; r2 < 4; r2++) {
            int row = w * 16 + q * 4 + r2;
            int pos = base + row;
            if (pos < E)
                m_out[(size_t)pos * 64 + nt * 16 + ml] = f2bf(acc2[nt][r2] + b2c[nt]);
        }
    }
}

// ---------------- root weight: h = (add_h?h:0) + hn @ Wr  (MFMA) ----------------
__global__ __launch_bounds__(512) void k_root(
    const u16* __restrict__ hn, const u16* __restrict__ Wrs,
    float* __restrict__ h, int add_h, int n) {
    __shared__ short sA[8 * 1024];   // 16 KB: 8 groups x (8 chunks x 128)
    int t = threadIdx.x;
    int base = blockIdx.x * 128;
    {
        int r = t >> 2, s = t & 3;
        int pos = base + r;
        int g = r >> 4, m = r & 15;
        short* grp = sA + g * 1024;
        bool act = pos < n;
        uint4 z4 = make_uint4(0, 0, 0, 0);
        const uint4* pd = (const uint4*)(hn + (size_t)(act ? pos : 0) * 64);
        uint4 d0 = act ? pd[2 * s] : z4;
        uint4 d1 = act ? pd[2 * s + 1] : z4;
        int ch = (s >> 1) * 4 + (s & 1) * 2;
        *((uint4*)(grp + ch * 128 + m * 8)) = d0;
        *((uint4*)(grp + (ch + 1) * 128 + m * 8)) = d1;
    }
    __syncthreads();
    int w = t >> 6, l = t & 63, q = l >> 4, ml = l & 15;
    short* arena = sA + w * 1024;
    floatx4 acc[4];
#pragma unroll
    for (int nt = 0; nt < 4; nt++) acc[nt] = floatx4{0.f, 0.f, 0.f, 0.f};
#pragma unroll
    for (int kt = 0; kt < 2; kt++) {
        short8 a = *((const short8*)(arena + (kt * 4 + q) * 128 + ml * 8));
#pragma unroll
        for (int nt = 0; nt < 4; nt++) {
            short8 bf = *((const short8*)(Wrs + (size_t)((kt * 4 + q) * 64 + nt * 16 + ml) * 8));
            acc[nt] = __builtin_amdgcn_mfma_f32_16x16x32_bf16(a, bf, acc[nt], 0, 0, 0);
        }
    }
#pragma unroll
    for (int nt = 0; nt < 4; nt++) {
#pragma unroll
        for (int r2 = 0; r2 < 4; r2++) {
            int pos = base + w * 16 + q * 4 + r2;
            if (pos < n) {
                size_t idx = (size_t)pos * 64 + nt * 16 + ml;
                float v = acc[nt][r2];
                h[idx] = add_h ? (h[idx] + v) : v;
            }
        }
    }
}

// ---------------- e += m (vectorized elementwise, bf16) ----------------
__global__ void k_eadd(u16* __restrict__ dst, const u16* __restrict__ src, long nv) {
    long i = (long)blockIdx.x * blockDim.x + threadIdx.x;
    if (i < nv) {
        uint4 a = ((const uint4*)dst)[i];
        uint4 b = ((const uint4*)src)[i];
        u32* pa = (u32*)&a;
        const u32* pb = (const u32*)&b;
        uint4 r;
        u32* pr = (u32*)&r;
#pragma unroll
        for (int k = 0; k < 4; k++) {
            float lo = bf2f((u16)(pa[k] & 0xffffu)) + bf2f((u16)(pb[k] & 0xffffu));
            float hi = bf2f((u16)(pa[k] >> 16)) + bf2f((u16)(pb[k] >> 16));
            pr[k] = (u32)f2bf(lo) | ((u32)f2bf(hi) << 16);
        }
        ((uint4*)dst)[i] = r;
    }
}

// ---------------- aggregation: pure online softmax over CSR ----------------
__global__ __launch_bounds__(256) void k_agg2(
    const u16* __restrict__ m_s, float* __restrict__ h,
    const int* __restrict__ offs, const float* __restrict__ tptr, int tidx,
    int n, int E) {
    int t = threadIdx.x, wid = t >> 6, lane = t & 63;
    float tv = tptr[tidx];
    for (int node = blockIdx.x * 4 + wid; node < n; node += gridDim.x * 4) {
        int p0 = clampi(offs[node], 0, E);
        int p1 = clampi(offs[node + 1], p0, E);
        float M = -1e30f, D = 0.f, S = 0.f;
        for (int p = p0; p < p1; p++) {
            float mv = bf2f(m_s[(size_t)p * 64 + lane]);
            float lg = mv * tv;
            float Mn = fmaxf(M, lg);
            float a = __expf(M - Mn);
            float b = __expf(lg - Mn);
            D = D * a + b;
            S = S * a + mv * b;
            M = Mn;
        }
        if (p1 > p0) h[(size_t)node * 64 + lane] += S / D;
    }
}

// ---------------- launcher ----------------
extern "C" void kernel_launch(void* const* d_in, const int* in_sizes, int n_in,
                              void* d_out, int out_size, void* d_ws, size_t ws_size,
                              hipStream_t stream) {
    float* outp = (float*)d_out;
    int FB = (out_size + 255) / 256;

    if (n_in != 17) {
        k_fill<<<FB, 256, 0, stream>>>(outp, out_size, 3.0f);
        return;
    }

    const float* x    = (const float*)d_in[0];
    const int*   ei   = (const int*)d_in[1];
    const float* ea   = (const float*)d_in[2];
    const float* nW   = (const float*)d_in[3];
    const float* nb   = (const float*)d_in[4];
    const float* eW   = (const float*)d_in[5];
    const float* eb   = (const float*)d_in[6];
    const float* cW1  = (const float*)d_in[7];
    const float* cb1  = (const float*)d_in[8];
    const float* cW2  = (const float*)d_in[9];
    const float* cb2  = (const float*)d_in[10];
    const float* cWr  = (const float*)d_in[11];
    const float* ct   = (const float*)d_in[12];
    const float* lng  = (const float*)d_in[13];
    const float* lnb  = (const float*)d_in[14];
    const float* elng = (const float*)d_in[15];
    const float* elnb = (const float*)d_in[16];

    const int n = in_sizes[0] / 128;   // 50000
    const int E = in_sizes[2] / 16;    // 500000

    char* ws = (char*)d_ws;
    size_t o = 0;
    auto alloc = [&](size_t bytes) -> void* {
        void* p = ws + o;
        o += (bytes + 255) & ~(size_t)255;
        return p;
    };
    int*   flag   = (int*)alloc(256);
    int*   deg    = (int*)alloc((size_t)n * 4);
    int*   offs   = (int*)alloc((size_t)(n + 1) * 4);
    int*   cursor = (int*)alloc((size_t)n * 4);
    int*   bsum   = (int*)alloc(256 * 4);
    int*   perm   = (int*)alloc((size_t)E * 4);
    int*   srcs   = (int*)alloc((size_t)E * 4);
    int*   dsts   = (int*)alloc((size_t)E * 4);
    float* h      = (float*)alloc((size_t)n * 64 * 4);
    u16*   hn     = (u16*)alloc((size_t)n * 64 * 2);
    u16*   bufA   = (u16*)alloc((size_t)E * 64 * 2);
    u16*   bufB   = (u16*)alloc((size_t)E * 64 * 2);
    u16*   W1s    = (u16*)alloc((size_t)3 * 24576 * 2);
    u16*   W2s    = (u16*)alloc((size_t)3 * 8192 * 2);
    u16*   Wrs    = (u16*)alloc((size_t)3 * 4096 * 2);

    k_fill<<<FB, 256, 0, stream>>>(outp, out_size, 1.0f);
    if (o > ws_size) {
        k_fill<<<FB, 256, 0, stream>>>(outp, out_size, 2.0f);
        return;
    }

    int SB = (n + 255) / 256;
    k_detect<<<1, 256, 0, stream>>>(ei, E, flag);
    k_zero<<<SB, 256, 0, stream>>>(deg, n);
    k_hist<<<(E + 255) / 256, 256, 0, stream>>>(ei, flag, deg, E, n);
    k_scan1<<<SB, 256, 0, stream>>>(deg, offs, bsum, n);
    k_scan2<<<1, 256, 0, stream>>>(bsum, SB);
    k_scan3<<<SB, 256, 0, stream>>>(offs, bsum, cursor, n, E);
    k_scatter<<<(E + 255) / 256, 256, 0, stream>>>(ei, flag, cursor, perm, srcs, dsts, E, n);
    k_swz<<<(3 * 24576 + 255) / 256, 256, 0, stream>>>(cW1, cW2, cWr, W1s, W2s, Wrs);
    k_node_enc<<<1024, 256, 0, stream>>>(x, nW, nb, h, hn, n);
    k_edge_enc<<<2048, 256, 0, stream>>>(ea, perm, eW, eb, bufA, E);

    // Buffer schedule (ping-pong, no copies):
    //  L0: mlp(in=bufA[e0])      -> bufB(m1); agg reads bufB; e_cur = bufB
    //  L1: mlp(in=bufB)          -> bufA(m2); agg reads bufA; eadd: bufB += bufA (e_cur = bufB)
    //  L2: mlp(in=bufB)          -> bufA(m3); agg reads bufA
    int MB = (E + TILE - 1) / TILE;
    int RB = (n + 127) / 128;
    int AB = (n + 3) / 4;
    long nv = (long)E * 64 / 8;
    int VB = (int)((nv + 255) / 256);

    const u16* mlp_in[3]  = { bufA, bufB, bufB };
    u16*       mlp_out[3] = { bufB, bufA, bufA };

    for (int i = 0; i < 3; i++) {
        if (i > 0)
            k_lnorm_bf<<<512, 256, 0, stream>>>(h, lng + (size_t)i * 64, lnb + (size_t)i * 64, hn, n);
        k_mlp<<<MB, 512, 0, stream>>>(
            hn, mlp_in[i], dsts, srcs,
            W1s + (size_t)i * 24576, cb1 + (size_t)i * 128,
            W2s + (size_t)i * 8192, cb2 + (size_t)i * 64,
            elng + (size_t)((i > 0) ? (i - 1) : 0) * 64,
            elnb + (size_t)((i > 0) ? (i - 1) : 0) * 64,
            (i > 0) ? 1 : 0, mlp_out[i], E);
        k_root<<<RB, 512, 0, stream>>>(hn, Wrs + (size_t)i * 4096, h, (i > 0) ? 1 : 0, n);
        k_agg2<<<AB, 256, 0, stream>>>(mlp_out[i], h, offs, ct, i, n, E);
        if (i == 1)
            k_eadd<<<VB, 256, 0, stream>>>(bufB, bufA, nv);
    }
    k_lnorm_out<<<512, 256, 0, stream>>>(h, lng, lnb, outp, n);
}

// Round 8
// 865.591 us; speedup vs baseline: 32.6630x; 1.1246x over previous
//
#include <hip/hip_runtime.h>

typedef unsigned short u16;
typedef unsigned int u32;
typedef __attribute__((ext_vector_type(8))) short short8;
typedef __attribute__((ext_vector_type(4))) float floatx4;

#define LN_EPS 1e-5f

__device__ __forceinline__ float bf2f(u16 u) {
    union { u32 i; float f; } v; v.i = ((u32)u) << 16; return v.f;
}
__device__ __forceinline__ u16 f2bf(float f) {
    union { u32 i; float f; } v; v.f = f;
    u32 x = v.i;
    return (u16)((x + 0x7fffu + ((x >> 16) & 1u)) >> 16);
}
__device__ __forceinline__ int clampi(int v, int lo, int hi) {
    return v < lo ? lo : (v > hi ? hi : v);
}

// Diagnostic fill (f32).
__global__ void k_fill(float* __restrict__ out, int nel, float val) {
    int i = blockIdx.x * blockDim.x + threadIdx.x;
    if (i < nel) out[i] = val;
}

// ---------------- preprocessing ----------------
__global__ void k_zero(int* p, int n) {
    int i = blockIdx.x * blockDim.x + threadIdx.x;
    if (i < n) p[i] = 0;
}

__global__ void k_detect(const int* __restrict__ ei, int E, int* __restrict__ flag) {
    __shared__ int any;
    if (threadIdx.x == 0) any = 0;
    __syncthreads();
    int lim = (E < 4096) ? E : 4096;
    int v = 0;
    for (int i = threadIdx.x; i < lim; i += 256) v |= ei[2 * i + 1];
    if (v) atomicOr(&any, 1);
    __syncthreads();
    if (threadIdx.x == 0) flag[0] = (any == 0) ? 1 : 0;
}

__global__ void k_hist(const int* __restrict__ ei, const int* __restrict__ flag,
                       int* __restrict__ deg, int E, int n) {
    int e = blockIdx.x * blockDim.x + threadIdx.x;
    if (e < E) {
        int d = flag[0] ? ei[2 * ((size_t)E + e)] : ei[(size_t)E + e];
        atomicAdd(&deg[clampi(d, 0, n - 1)], 1);
    }
}

__global__ void k_scan1(const int* __restrict__ deg, int* __restrict__ offs,
                        int* __restrict__ bsum, int n) {
    __shared__ int s[256];
    int t = threadIdx.x;
    int i = blockIdx.x * 256 + t;
    int v = (i < n) ? deg[i] : 0;
    s[t] = v; __syncthreads();
    for (int off = 1; off < 256; off <<= 1) {
        int x = (t >= off) ? s[t - off] : 0;
        __syncthreads();
        s[t] += x;
        __syncthreads();
    }
    if (i < n) offs[i] = s[t] - v;
    if (t == 255) bsum[blockIdx.x] = s[255];
}

__global__ void k_scan2(int* bsum, int nb) {
    __shared__ int s[256];
    int t = threadIdx.x;
    int v = (t < nb) ? bsum[t] : 0;
    s[t] = v; __syncthreads();
    for (int off = 1; off < 256; off <<= 1) {
        int x = (t >= off) ? s[t - off] : 0;
        __syncthreads();
        s[t] += x;
        __syncthreads();
    }
    if (t < nb) bsum[t] = s[t] - v;
}

__global__ void k_scan3(int* __restrict__ offs, const int* __restrict__ bsum,
                        int* __restrict__ cursor, int n, int E) {
    int i = blockIdx.x * 256 + threadIdx.x;
    if (i < n) {
        int v = offs[i] + bsum[blockIdx.x];
        offs[i] = v;
        cursor[i] = v;
    }
    if (i == 0) offs[n] = E;
}

__global__ void k_scatter(const int* __restrict__ ei, const int* __restrict__ flag,
                          int* __restrict__ cursor,
                          int* __restrict__ perm, int* __restrict__ srcs,
                          int* __restrict__ dsts, int E, int n) {
    int e = blockIdx.x * blockDim.x + threadIdx.x;
    if (e < E) {
        int sv, dv;
        if (flag[0]) {
            sv = ei[2 * (size_t)e];
            dv = ei[2 * ((size_t)E + e)];
        } else {
            sv = ei[e];
            dv = ei[(size_t)E + e];
        }
        sv = clampi(sv, 0, n - 1);
        dv = clampi(dv, 0, n - 1);
        int p = clampi(atomicAdd(&cursor[dv], 1), 0, E - 1);
        perm[p] = e;
        srcs[p] = sv;
        dsts[p] = dv;
    }
}

// Pre-swizzle f32 weights into bf16 MFMA B-fragment order:
// B[k][n], k = kt*32 + q*8 + j  ->  idx = ((kt*4+q)*N + n)*8 + j
__global__ void k_swz(const float* __restrict__ W1, const float* __restrict__ W2,
                      const float* __restrict__ Wr,
                      u16* __restrict__ W1s, u16* __restrict__ W2s,
                      u16* __restrict__ Wrs) {
    int i = blockIdx.x * blockDim.x + threadIdx.x;
    if (i < 3 * 24576) {
        int l = i / 24576, rem = i % 24576;
        int k = rem / 128, n = rem % 128;
        int kt = k >> 5, q = (k >> 3) & 3, j = k & 7;
        W1s[l * 24576 + ((kt * 4 + q) * 128 + n) * 8 + j] = f2bf(W1[i]);
    }
    if (i < 3 * 8192) {
        int l = i / 8192, rem = i % 8192;
        int k = rem / 64, n = rem % 64;
        int kt = k >> 5, q = (k >> 3) & 3, j = k & 7;
        W2s[l * 8192 + ((kt * 4 + q) * 64 + n) * 8 + j] = f2bf(W2[i]);
    }
    if (i < 3 * 4096) {
        int l = i / 4096, rem = i % 4096;
        int k = rem / 64, n = rem % 64;
        int kt = k >> 5, q = (k >> 3) & 3, j = k & 7;
        Wrs[l * 4096 + ((kt * 4 + q) * 64 + n) * 8 + j] = f2bf(Wr[i]);
    }
}

// ---------------- encoders (f32 inputs) ----------------
__global__ __launch_bounds__(256) void k_node_enc(
    const float* __restrict__ x, const float* __restrict__ W, const float* __restrict__ bias,
    float* __restrict__ h, u16* __restrict__ hn, int n) {
    __shared__ float sW[128 * 64];   // 32 KB
    int t = threadIdx.x;
    for (int i = t; i < 128 * 64; i += 256) sW[i] = W[i];
    __syncthreads();
    int wid = t >> 6, lane = t & 63;
    float bc = bias[lane];
    for (int row = blockIdx.x * 4 + wid; row < n; row += gridDim.x * 4) {
        float2 pr = ((const float2*)(x + (size_t)row * 128))[lane];
        float acc = bc;
#pragma unroll
        for (int k = 0; k < 128; k++) {
            float f = __shfl((k & 1) ? pr.y : pr.x, k >> 1);
            acc += f * sW[k * 64 + lane];
        }
        h[(size_t)row * 64 + lane] = acc;
        hn[(size_t)row * 64 + lane] = f2bf(acc);
    }
}

__global__ __launch_bounds__(256) void k_edge_enc(
    const float* __restrict__ ea, const int* __restrict__ perm,
    const float* __restrict__ W, const float* __restrict__ bias,
    u16* __restrict__ e_s, int E) {
    __shared__ float sW[16 * 64];    // 4 KB
    int t = threadIdx.x;
    for (int i = t; i < 16 * 64; i += 256) sW[i] = W[i];
    __syncthreads();
    int wid = t >> 6, lane = t & 63;
    float bc = bias[lane];
    for (int pos = blockIdx.x * 4 + wid; pos < E; pos += gridDim.x * 4) {
        int e = perm[pos];
        float pr = (lane < 16) ? ea[(size_t)e * 16 + lane] : 0.f;
        float acc = bc;
#pragma unroll
        for (int k = 0; k < 16; k++) {
            float f = __shfl(pr, k);
            acc += f * sW[k * 64 + lane];
        }
        e_s[(size_t)pos * 64 + lane] = f2bf(acc);
    }
}

// ---------------- layernorm: bf16-out (hn producer) and f32-out (final) ----------------
__global__ __launch_bounds__(256) void k_lnorm_bf(
    const float* __restrict__ h, const float* __restrict__ g, const float* __restrict__ b,
    u16* __restrict__ out, int n) {
    int t = threadIdx.x, wid = t >> 6, lane = t & 63;
    float gc = g[lane], bc = b[lane];
    for (int row = blockIdx.x * 4 + wid; row < n; row += gridDim.x * 4) {
        float v = h[(size_t)row * 64 + lane];
        float s = v;
#pragma unroll
        for (int o = 32; o > 0; o >>= 1) s += __shfl_xor(s, o);
        float mu = s * (1.f / 64.f);
        float d = v - mu;
        float s2 = d * d;
#pragma unroll
        for (int o = 32; o > 0; o >>= 1) s2 += __shfl_xor(s2, o);
        float inv = rsqrtf(s2 * (1.f / 64.f) + LN_EPS);
        float r = fmaxf(d * inv * gc + bc, 0.f);
        out[(size_t)row * 64 + lane] = f2bf(r);
    }
}

__global__ __launch_bounds__(256) void k_lnorm_out(
    const float* __restrict__ h, const float* __restrict__ g, const float* __restrict__ b,
    float* __restrict__ out, int n) {
    int t = threadIdx.x, wid = t >> 6, lane = t & 63;
    float gc = g[lane], bc = b[lane];
    for (int row = blockIdx.x * 4 + wid; row < n; row += gridDim.x * 4) {
        float v = h[(size_t)row * 64 + lane];
        float s = v;
#pragma unroll
        for (int o = 32; o > 0; o >>= 1) s += __shfl_xor(s, o);
        float mu = s * (1.f / 64.f);
        float d = v - mu;
        float s2 = d * d;
#pragma unroll
        for (int o = 32; o > 0; o >>= 1) s2 += __shfl_xor(s2, o);
        float inv = rsqrtf(s2 * (1.f / 64.f) + LN_EPS);
        out[(size_t)row * 64 + lane] = fmaxf(d * inv * gc + bc, 0.f);
    }
}

// ---------------- edge MLP (MFMA, barrier-free) ----------------
// Tile = 128 edges, 512 threads = 8 waves; each wave owns 16 edges.
// A-fragments loaded DIRECTLY from global (lane (q,ml) reads the aligned 16B
// holding A[ml][kt*32+q*8..+7]); edge-LN via q-shuffles; hidden/m repack via
// wave-private stride-136 LDS rows (bank-staggered). No __syncthreads.
#define TILE 128
#define HSTR 136
__global__ __launch_bounds__(512, 4) void k_mlp(
    const u16* __restrict__ hn, const u16* __restrict__ e_s,
    const int* __restrict__ dsts, const int* __restrict__ srcs,
    const u16* __restrict__ W1s, const float* __restrict__ b1,
    const u16* __restrict__ W2s, const float* __restrict__ b2,
    const float* __restrict__ elng, const float* __restrict__ elnb,
    int ln_edge, u16* __restrict__ m_out, int E) {
    __shared__ short sH[8 * 16 * HSTR];   // 34 KB

    int t = threadIdx.x;
    int w = t >> 6, l = t & 63, q = l >> 4, ml = l & 15;
    int base = blockIdx.x * TILE + w * 16;
    int pos = base + ml;
    bool act = pos < E;
    int pp = act ? pos : 0;
    int dn = act ? dsts[pos] : 0;
    int sn = act ? srcs[pos] : 0;

    // ---- A-fragments direct from global ----
    short8 a[6];
    a[0] = *(const short8*)(hn + (size_t)dn * 64 + q * 8);
    a[1] = *(const short8*)(hn + (size_t)dn * 64 + 32 + q * 8);
    a[2] = *(const short8*)(hn + (size_t)sn * 64 + q * 8);
    a[3] = *(const short8*)(hn + (size_t)sn * 64 + 32 + q * 8);
    short8 e0 = *(const short8*)(e_s + (size_t)pp * 64 + q * 8);
    short8 e1 = *(const short8*)(e_s + (size_t)pp * 64 + 32 + q * 8);

    if (ln_edge) {
        float ev[16];
        float sm = 0.f, sq = 0.f;
#pragma unroll
        for (int i = 0; i < 8; i++) {
            float f0 = bf2f((u16)e0[i]);
            float f1 = bf2f((u16)e1[i]);
            ev[i] = f0; ev[8 + i] = f1;
            sm += f0 + f1; sq += f0 * f0 + f1 * f1;
        }
        // reduce across the 4 q-lanes of this row (lanes differ in bits 4,5)
        sm += __shfl_xor(sm, 16); sm += __shfl_xor(sm, 32);
        sq += __shfl_xor(sq, 16); sq += __shfl_xor(sq, 32);
        float mu = sm * (1.f / 64.f);
        float var = sq * (1.f / 64.f) - mu * mu;
        float inv = rsqrtf(fmaxf(var, 0.f) + LN_EPS);
#pragma unroll
        for (int i = 0; i < 8; i++) {
            int c0 = q * 8 + i, c1 = 32 + q * 8 + i;
            a[4][i] = (short)f2bf((ev[i] - mu) * inv * elng[c0] + elnb[c0]);
            a[5][i] = (short)f2bf((ev[8 + i] - mu) * inv * elng[c1] + elnb[c1]);
        }
    } else {
        a[4] = e0; a[5] = e1;
    }

    // ---- GEMM1: [16 x 192] @ W1[192,128] ----
    float b1c[8], b2c[4];
#pragma unroll
    for (int nt = 0; nt < 8; nt++) b1c[nt] = b1[nt * 16 + ml];
#pragma unroll
    for (int nt = 0; nt < 4; nt++) b2c[nt] = b2[nt * 16 + ml];

    floatx4 acc[8];
#pragma unroll
    for (int nt = 0; nt < 8; nt++) acc[nt] = floatx4{0.f, 0.f, 0.f, 0.f};
#pragma unroll
    for (int kt = 0; kt < 6; kt++) {
#pragma unroll
        for (int nt = 0; nt < 8; nt++) {
            short8 bf = *((const short8*)(W1s + (size_t)((kt * 4 + q) * 128 + nt * 16 + ml) * 8));
            acc[nt] = __builtin_amdgcn_mfma_f32_16x16x32_bf16(a[kt], bf, acc[nt], 0, 0, 0);
        }
    }

    // ---- hidden repack: C-layout -> row-major stride-HSTR (wave-private) ----
    short* arena = sH + w * 16 * HSTR;
#pragma unroll
    for (int nt = 0; nt < 8; nt++) {
#pragma unroll
        for (int r2 = 0; r2 < 4; r2++) {
            float v = fmaxf(acc[nt][r2] + b1c[nt], 0.f);
            ((u16*)arena)[(q * 4 + r2) * HSTR + nt * 16 + ml] = f2bf(v);
        }
    }

    // ---- GEMM2: [16 x 128] @ W2[128,64] ----
    floatx4 acc2[4];
#pragma unroll
    for (int nt = 0; nt < 4; nt++) acc2[nt] = floatx4{0.f, 0.f, 0.f, 0.f};
#pragma unroll
    for (int kt = 0; kt < 4; kt++) {
        short8 ah = *((const short8*)(arena + ml * HSTR + kt * 32 + q * 8));
#pragma unroll
        for (int nt = 0; nt < 4; nt++) {
            short8 bf = *((const short8*)(W2s + (size_t)((kt * 4 + q) * 64 + nt * 16 + ml) * 8));
            acc2[nt] = __builtin_amdgcn_mfma_f32_16x16x32_bf16(ah, bf, acc2[nt], 0, 0, 0);
        }
    }

    // ---- m transpose through arena, coalesced 16B stores ----
#pragma unroll
    for (int nt = 0; nt < 4; nt++) {
#pragma unroll
        for (int r2 = 0; r2 < 4; r2++) {
            ((u16*)arena)[(q * 4 + r2) * HSTR + nt * 16 + ml] = f2bf(acc2[nt][r2] + b2c[nt]);
        }
    }
    short8 m0 = *((const short8*)(arena + ml * HSTR + q * 16));
    short8 m1 = *((const short8*)(arena + ml * HSTR + q * 16 + 8));
    if (act) {
        *((short8*)(m_out + (size_t)pos * 64 + q * 16)) = m0;
        *((short8*)(m_out + (size_t)pos * 64 + q * 16 + 8)) = m1;
    }
}

// ---------------- root weight: h = (add_h?h:0) + hn @ Wr  (MFMA) ----------------
__global__ __launch_bounds__(512) void k_root(
    const u16* __restrict__ hn, const u16* __restrict__ Wrs,
    float* __restrict__ h, int add_h, int n) {
    __shared__ short sA[8 * 1024];   // 16 KB
    int t = threadIdx.x;
    int base = blockIdx.x * 128;
    {
        int r = t >> 2, s = t & 3;
        int pos = base + r;
        int g = r >> 4, m = r & 15;
        short* grp = sA + g * 1024;
        bool act = pos < n;
        uint4 z4 = make_uint4(0, 0, 0, 0);
        const uint4* pd = (const uint4*)(hn + (size_t)(act ? pos : 0) * 64);
        uint4 d0 = act ? pd[2 * s] : z4;
        uint4 d1 = act ? pd[2 * s + 1] : z4;
        int ch = (s >> 1) * 4 + (s & 1) * 2;
        *((uint4*)(grp + ch * 128 + m * 8)) = d0;
        *((uint4*)(grp + (ch + 1) * 128 + m * 8)) = d1;
    }
    __syncthreads();
    int w = t >> 6, l = t & 63, q = l >> 4, ml = l & 15;
    short* arena = sA + w * 1024;
    floatx4 acc[4];
#pragma unroll
    for (int nt = 0; nt < 4; nt++) acc[nt] = floatx4{0.f, 0.f, 0.f, 0.f};
#pragma unroll
    for (int kt = 0; kt < 2; kt++) {
        short8 a = *((const short8*)(arena + (kt * 4 + q) * 128 + ml * 8));
#pragma unroll
        for (int nt = 0; nt < 4; nt++) {
            short8 bf = *((const short8*)(Wrs + (size_t)((kt * 4 + q) * 64 + nt * 16 + ml) * 8));
            acc[nt] = __builtin_amdgcn_mfma_f32_16x16x32_bf16(a, bf, acc[nt], 0, 0, 0);
        }
    }
#pragma unroll
    for (int nt = 0; nt < 4; nt++) {
#pragma unroll
        for (int r2 = 0; r2 < 4; r2++) {
            int pos = base + w * 16 + q * 4 + r2;
            if (pos < n) {
                size_t idx = (size_t)pos * 64 + nt * 16 + ml;
                float v = acc[nt][r2];
                h[idx] = add_h ? (h[idx] + v) : v;
            }
        }
    }
}

// ---------------- e += m (vectorized elementwise, bf16) ----------------
__global__ void k_eadd(u16* __restrict__ dst, const u16* __restrict__ src, long nv) {
    long i = (long)blockIdx.x * blockDim.x + threadIdx.x;
    if (i < nv) {
        uint4 a = ((const uint4*)dst)[i];
        uint4 b = ((const uint4*)src)[i];
        u32* pa = (u32*)&a;
        const u32* pb = (const u32*)&b;
        uint4 r;
        u32* pr = (u32*)&r;
#pragma unroll
        for (int k = 0; k < 4; k++) {
            float lo = bf2f((u16)(pa[k] & 0xffffu)) + bf2f((u16)(pb[k] & 0xffffu));
            float hi = bf2f((u16)(pa[k] >> 16)) + bf2f((u16)(pb[k] >> 16));
            pr[k] = (u32)f2bf(lo) | ((u32)f2bf(hi) << 16);
        }
        ((uint4*)dst)[i] = r;
    }
}

// ---------------- aggregation: pure online softmax over CSR ----------------
__global__ __launch_bounds__(256) void k_agg2(
    const u16* __restrict__ m_s, float* __restrict__ h,
    const int* __restrict__ offs, const float* __restrict__ tptr, int tidx,
    int n, int E) {
    int t = threadIdx.x, wid = t >> 6, lane = t & 63;
    float tv = tptr[tidx];
    for (int node = blockIdx.x * 4 + wid; node < n; node += gridDim.x * 4) {
        int p0 = clampi(offs[node], 0, E);
        int p1 = clampi(offs[node + 1], p0, E);
        float M = -1e30f, D = 0.f, S = 0.f;
        for (int p = p0; p < p1; p++) {
            float mv = bf2f(m_s[(size_t)p * 64 + lane]);
            float lg = mv * tv;
            float Mn = fmaxf(M, lg);
            float a = __expf(M - Mn);
            float b = __expf(lg - Mn);
            D = D * a + b;
            S = S * a + mv * b;
            M = Mn;
        }
        if (p1 > p0) h[(size_t)node * 64 + lane] += S / D;
    }
}

// ---------------- launcher ----------------
extern "C" void kernel_launch(void* const* d_in, const int* in_sizes, int n_in,
                              void* d_out, int out_size, void* d_ws, size_t ws_size,
                              hipStream_t stream) {
    float* outp = (float*)d_out;
    int FB = (out_size + 255) / 256;

    if (n_in != 17) {
        k_fill<<<FB, 256, 0, stream>>>(outp, out_size, 3.0f);
        return;
    }

    const float* x    = (const float*)d_in[0];
    const int*   ei   = (const int*)d_in[1];
    const float* ea   = (const float*)d_in[2];
    const float* nW   = (const float*)d_in[3];
    const float* nb   = (const float*)d_in[4];
    const float* eW   = (const float*)d_in[5];
    const float* eb   = (const float*)d_in[6];
    const float* cW1  = (const float*)d_in[7];
    const float* cb1  = (const float*)d_in[8];
    const float* cW2  = (const float*)d_in[9];
    const float* cb2  = (const float*)d_in[10];
    const float* cWr  = (const float*)d_in[11];
    const float* ct   = (const float*)d_in[12];
    const float* lng  = (const float*)d_in[13];
    const float* lnb  = (const float*)d_in[14];
    const float* elng = (const float*)d_in[15];
    const float* elnb = (const float*)d_in[16];

    const int n = in_sizes[0] / 128;   // 50000
    const int E = in_sizes[2] / 16;    // 500000

    char* ws = (char*)d_ws;
    size_t o = 0;
    auto alloc = [&](size_t bytes) -> void* {
        void* p = ws + o;
        o += (bytes + 255) & ~(size_t)255;
        return p;
    };
    int*   flag   = (int*)alloc(256);
    int*   deg    = (int*)alloc((size_t)n * 4);
    int*   offs   = (int*)alloc((size_t)(n + 1) * 4);
    int*   cursor = (int*)alloc((size_t)n * 4);
    int*   bsum   = (int*)alloc(256 * 4);
    int*   perm   = (int*)alloc((size_t)E * 4);
    int*   srcs   = (int*)alloc((size_t)E * 4);
    int*   dsts   = (int*)alloc((size_t)E * 4);
    float* h      = (float*)alloc((size_t)n * 64 * 4);
    u16*   hn     = (u16*)alloc((size_t)n * 64 * 2);
    u16*   bufA   = (u16*)alloc((size_t)E * 64 * 2);
    u16*   bufB   = (u16*)alloc((size_t)E * 64 * 2);
    u16*   W1s    = (u16*)alloc((size_t)3 * 24576 * 2);
    u16*   W2s    = (u16*)alloc((size_t)3 * 8192 * 2);
    u16*   Wrs    = (u16*)alloc((size_t)3 * 4096 * 2);

    k_fill<<<FB, 256, 0, stream>>>(outp, out_size, 1.0f);
    if (o > ws_size) {
        k_fill<<<FB, 256, 0, stream>>>(outp, out_size, 2.0f);
        return;
    }

    int SB = (n + 255) / 256;
    k_detect<<<1, 256, 0, stream>>>(ei, E, flag);
    k_zero<<<SB, 256, 0, stream>>>(deg, n);
    k_hist<<<(E + 255) / 256, 256, 0, stream>>>(ei, flag, deg, E, n);
    k_scan1<<<SB, 256, 0, stream>>>(deg, offs, bsum, n);
    k_scan2<<<1, 256, 0, stream>>>(bsum, SB);
    k_scan3<<<SB, 256, 0, stream>>>(offs, bsum, cursor, n, E);
    k_scatter<<<(E + 255) / 256, 256, 0, stream>>>(ei, flag, cursor, perm, srcs, dsts, E, n);
    k_swz<<<(3 * 24576 + 255) / 256, 256, 0, stream>>>(cW1, cW2, cWr, W1s, W2s, Wrs);
    k_node_enc<<<1024, 256, 0, stream>>>(x, nW, nb, h, hn, n);
    k_edge_enc<<<2048, 256, 0, stream>>>(ea, perm, eW, eb, bufA, E);

    // Buffer schedule (ping-pong, no copies):
    //  L0: mlp(in=bufA[e0]) -> bufB(m1); agg reads bufB
    //  L1: mlp(in=bufB)     -> bufA(m2); agg reads bufA; eadd: bufB += bufA
    //  L2: mlp(in=bufB)     -> bufA(m3); agg reads bufA
    int MB = (E + TILE - 1) / TILE;
    int RB = (n + 127) / 128;
    int AB = (n + 3) / 4;
    long nv = (long)E * 64 / 8;
    int VB = (int)((nv + 255) / 256);

    const u16* mlp_in[3]  = { bufA, bufB, bufB };
    u16*       mlp_out[3] = { bufB, bufA, bufA };

    for (int i = 0; i < 3; i++) {
        if (i > 0)
            k_lnorm_bf<<<512, 256, 0, stream>>>(h, lng + (size_t)i * 64, lnb + (size_t)i * 64, hn, n);
        k_mlp<<<MB, 512, 0, stream>>>(
            hn, mlp_in[i], dsts, srcs,
            W1s + (size_t)i * 24576, cb1 + (size_t)i * 128,
            W2s + (size_t)i * 8192, cb2 + (size_t)i * 64,
            elng + (size_t)((i > 0) ? (i - 1) : 0) * 64,
            elnb + (size_t)((i > 0) ? (i - 1) : 0) * 64,
            (i > 0) ? 1 : 0, mlp_out[i], E);
        k_root<<<RB, 512, 0, stream>>>(hn, Wrs + (size_t)i * 4096, h, (i > 0) ? 1 : 0, n);
        k_agg2<<<AB, 256, 0, stream>>>(mlp_out[i], h, offs, ct, i, n, E);
        if (i == 1)
            k_eadd<<<VB, 256, 0, stream>>>(bufB, bufA, nv);
    }
    k_lnorm_out<<<512, 256, 0, stream>>>(h, lng, lnb, outp, n);
}

// Round 9
// 770.739 us; speedup vs baseline: 36.6827x; 1.1231x over previous
//
#include <hip/hip_runtime.h>

typedef unsigned short u16;
typedef unsigned int u32;
typedef __attribute__((ext_vector_type(8))) short short8;
typedef __attribute__((ext_vector_type(4))) float floatx4;

#define LN_EPS 1e-5f

__device__ __forceinline__ float bf2f(u16 u) {
    union { u32 i; float f; } v; v.i = ((u32)u) << 16; return v.f;
}
__device__ __forceinline__ u16 f2bf(float f) {
    union { u32 i; float f; } v; v.f = f;
    u32 x = v.i;
    return (u16)((x + 0x7fffu + ((x >> 16) & 1u)) >> 16);
}
__device__ __forceinline__ int clampi(int v, int lo, int hi) {
    return v < lo ? lo : (v > hi ? hi : v);
}

// Diagnostic fill (f32).
__global__ void k_fill(float* __restrict__ out, int nel, float val) {
    int i = blockIdx.x * blockDim.x + threadIdx.x;
    if (i < nel) out[i] = val;
}

// ---------------- preprocessing ----------------
__global__ void k_zero(int* p, int n) {
    int i = blockIdx.x * blockDim.x + threadIdx.x;
    if (i < n) p[i] = 0;
}

__global__ void k_detect(const int* __restrict__ ei, int E, int* __restrict__ flag) {
    __shared__ int any;
    if (threadIdx.x == 0) any = 0;
    __syncthreads();
    int lim = (E < 4096) ? E : 4096;
    int v = 0;
    for (int i = threadIdx.x; i < lim; i += 256) v |= ei[2 * i + 1];
    if (v) atomicOr(&any, 1);
    __syncthreads();
    if (threadIdx.x == 0) flag[0] = (any == 0) ? 1 : 0;
}

__global__ void k_hist(const int* __restrict__ ei, const int* __restrict__ flag,
                       int* __restrict__ deg, int E, int n) {
    int e = blockIdx.x * blockDim.x + threadIdx.x;
    if (e < E) {
        int d = flag[0] ? ei[2 * ((size_t)E + e)] : ei[(size_t)E + e];
        atomicAdd(&deg[clampi(d, 0, n - 1)], 1);
    }
}

__global__ void k_scan1(const int* __restrict__ deg, int* __restrict__ offs,
                        int* __restrict__ bsum, int n) {
    __shared__ int s[256];
    int t = threadIdx.x;
    int i = blockIdx.x * 256 + t;
    int v = (i < n) ? deg[i] : 0;
    s[t] = v; __syncthreads();
    for (int off = 1; off < 256; off <<= 1) {
        int x = (t >= off) ? s[t - off] : 0;
        __syncthreads();
        s[t] += x;
        __syncthreads();
    }
    if (i < n) offs[i] = s[t] - v;
    if (t == 255) bsum[blockIdx.x] = s[255];
}

__global__ void k_scan2(int* bsum, int nb) {
    __shared__ int s[256];
    int t = threadIdx.x;
    int v = (t < nb) ? bsum[t] : 0;
    s[t] = v; __syncthreads();
    for (int off = 1; off < 256; off <<= 1) {
        int x = (t >= off) ? s[t - off] : 0;
        __syncthreads();
        s[t] += x;
        __syncthreads();
    }
    if (t < nb) bsum[t] = s[t] - v;
}

__global__ void k_scan3(int* __restrict__ offs, const int* __restrict__ bsum,
                        int* __restrict__ cursor, int n, int E) {
    int i = blockIdx.x * 256 + threadIdx.x;
    if (i < n) {
        int v = offs[i] + bsum[blockIdx.x];
        offs[i] = v;
        cursor[i] = v;
    }
    if (i == 0) offs[n] = E;
}

__global__ void k_scatter(const int* __restrict__ ei, const int* __restrict__ flag,
                          int* __restrict__ cursor,
                          int* __restrict__ perm, int* __restrict__ srcs,
                          int* __restrict__ dsts, int E, int n) {
    int e = blockIdx.x * blockDim.x + threadIdx.x;
    if (e < E) {
        int sv, dv;
        if (flag[0]) {
            sv = ei[2 * (size_t)e];
            dv = ei[2 * ((size_t)E + e)];
        } else {
            sv = ei[e];
            dv = ei[(size_t)E + e];
        }
        sv = clampi(sv, 0, n - 1);
        dv = clampi(dv, 0, n - 1);
        int p = clampi(atomicAdd(&cursor[dv], 1), 0, E - 1);
        perm[p] = e;
        srcs[p] = sv;
        dsts[p] = dv;
    }
}

// Pre-swizzle f32 weights into bf16 MFMA B-fragment order:
// B[k][n], k = kt*32 + q*8 + j  ->  idx = ((kt*4+q)*N + n)*8 + j
__global__ void k_swz(const float* __restrict__ W1, const float* __restrict__ W2,
                      const float* __restrict__ Wr,
                      u16* __restrict__ W1s, u16* __restrict__ W2s,
                      u16* __restrict__ Wrs) {
    int i = blockIdx.x * blockDim.x + threadIdx.x;
    if (i < 3 * 24576) {
        int l = i / 24576, rem = i % 24576;
        int k = rem / 128, n = rem % 128;
        int kt = k >> 5, q = (k >> 3) & 3, j = k & 7;
        W1s[l * 24576 + ((kt * 4 + q) * 128 + n) * 8 + j] = f2bf(W1[i]);
    }
    if (i < 3 * 8192) {
        int l = i / 8192, rem = i % 8192;
        int k = rem / 64, n = rem % 64;
        int kt = k >> 5, q = (k >> 3) & 3, j = k & 7;
        W2s[l * 8192 + ((kt * 4 + q) * 64 + n) * 8 + j] = f2bf(W2[i]);
    }
    if (i < 3 * 4096) {
        int l = i / 4096, rem = i % 4096;
        int k = rem / 64, n = rem % 64;
        int kt = k >> 5, q = (k >> 3) & 3, j = k & 7;
        Wrs[l * 4096 + ((kt * 4 + q) * 64 + n) * 8 + j] = f2bf(Wr[i]);
    }
}

// ---------------- encoders (f32 inputs) ----------------
__global__ __launch_bounds__(256) void k_node_enc(
    const float* __restrict__ x, const float* __restrict__ W, const float* __restrict__ bias,
    float* __restrict__ h, u16* __restrict__ hn, int n) {
    __shared__ float sW[128 * 64];   // 32 KB
    int t = threadIdx.x;
    for (int i = t; i < 128 * 64; i += 256) sW[i] = W[i];
    __syncthreads();
    int wid = t >> 6, lane = t & 63;
    float bc = bias[lane];
    for (int row = blockIdx.x * 4 + wid; row < n; row += gridDim.x * 4) {
        float2 pr = ((const float2*)(x + (size_t)row * 128))[lane];
        float acc = bc;
#pragma unroll
        for (int k = 0; k < 128; k++) {
            float f = __shfl((k & 1) ? pr.y : pr.x, k >> 1);
            acc += f * sW[k * 64 + lane];
        }
        h[(size_t)row * 64 + lane] = acc;
        hn[(size_t)row * 64 + lane] = f2bf(acc);
    }
}

// Thread-per-(edge, 16-ch quarter): fully independent threads, no shuffles.
__global__ __launch_bounds__(256) void k_edge_enc(
    const float* __restrict__ ea, const int* __restrict__ perm,
    const float* __restrict__ W, const float* __restrict__ bias,
    u16* __restrict__ e_s, int E) {
    __shared__ float4 sW4[16 * 16];   // W[16][64] as float4 [k][c/4], 4 KB
    int t = threadIdx.x;
    if (t < 256) sW4[t] = ((const float4*)W)[t];
    __syncthreads();
    int gid = blockIdx.x * 256 + t;
    int eidx = gid >> 2, qq = gid & 3;
    if (eidx >= E) return;
    int e = perm[eidx];
    const float4* row4 = (const float4*)(ea + (size_t)e * 16);
    float4 r4[4];
    r4[0] = row4[0]; r4[1] = row4[1]; r4[2] = row4[2]; r4[3] = row4[3];
    const float* row = (const float*)r4;
    float4 acc[4];
#pragma unroll
    for (int j = 0; j < 4; j++) acc[j] = ((const float4*)bias)[qq * 4 + j];
#pragma unroll
    for (int k = 0; k < 16; k++) {
        float rv = row[k];
#pragma unroll
        for (int j = 0; j < 4; j++) {
            float4 wv = sW4[k * 16 + qq * 4 + j];
            acc[j].x += rv * wv.x; acc[j].y += rv * wv.y;
            acc[j].z += rv * wv.z; acc[j].w += rv * wv.w;
        }
    }
    u32 pk[8];
#pragma unroll
    for (int j = 0; j < 4; j++) {
        pk[2 * j]     = (u32)f2bf(acc[j].x) | ((u32)f2bf(acc[j].y) << 16);
        pk[2 * j + 1] = (u32)f2bf(acc[j].z) | ((u32)f2bf(acc[j].w) << 16);
    }
    uint4* outp = (uint4*)(e_s + (size_t)eidx * 64 + qq * 16);
    outp[0] = make_uint4(pk[0], pk[1], pk[2], pk[3]);
    outp[1] = make_uint4(pk[4], pk[5], pk[6], pk[7]);
}

// ---------------- layernorm: bf16-out (hn producer) and f32-out (final) ----------------
__global__ __launch_bounds__(256) void k_lnorm_bf(
    const float* __restrict__ h, const float* __restrict__ g, const float* __restrict__ b,
    u16* __restrict__ out, int n) {
    int t = threadIdx.x, wid = t >> 6, lane = t & 63;
    float gc = g[lane], bc = b[lane];
    for (int row = blockIdx.x * 4 + wid; row < n; row += gridDim.x * 4) {
        float v = h[(size_t)row * 64 + lane];
        float s = v;
#pragma unroll
        for (int o = 32; o > 0; o >>= 1) s += __shfl_xor(s, o);
        float mu = s * (1.f / 64.f);
        float d = v - mu;
        float s2 = d * d;
#pragma unroll
        for (int o = 32; o > 0; o >>= 1) s2 += __shfl_xor(s2, o);
        float inv = rsqrtf(s2 * (1.f / 64.f) + LN_EPS);
        float r = fmaxf(d * inv * gc + bc, 0.f);
        out[(size_t)row * 64 + lane] = f2bf(r);
    }
}

__global__ __launch_bounds__(256) void k_lnorm_out(
    const float* __restrict__ h, const float* __restrict__ g, const float* __restrict__ b,
    float* __restrict__ out, int n) {
    int t = threadIdx.x, wid = t >> 6, lane = t & 63;
    float gc = g[lane], bc = b[lane];
    for (int row = blockIdx.x * 4 + wid; row < n; row += gridDim.x * 4) {
        float v = h[(size_t)row * 64 + lane];
        float s = v;
#pragma unroll
        for (int o = 32; o > 0; o >>= 1) s += __shfl_xor(s, o);
        float mu = s * (1.f / 64.f);
        float d = v - mu;
        float s2 = d * d;
#pragma unroll
        for (int o = 32; o > 0; o >>= 1) s2 += __shfl_xor(s2, o);
        float inv = rsqrtf(s2 * (1.f / 64.f) + LN_EPS);
        out[(size_t)row * 64 + lane] = fmaxf(d * inv * gc + bc, 0.f);
    }
}

// ---------------- edge MLP (MFMA, barrier-free) ----------------
#define TILE 128
#define HSTR 136
__global__ __launch_bounds__(512, 4) void k_mlp(
    const u16* __restrict__ hn, const u16* __restrict__ e_s,
    const int* __restrict__ dsts, const int* __restrict__ srcs,
    const u16* __restrict__ W1s, const float* __restrict__ b1,
    const u16* __restrict__ W2s, const float* __restrict__ b2,
    const float* __restrict__ elng, const float* __restrict__ elnb,
    int ln_edge, u16* __restrict__ m_out, int E) {
    __shared__ short sH[8 * 16 * HSTR];   // 34 KB

    int t = threadIdx.x;
    int w = t >> 6, l = t & 63, q = l >> 4, ml = l & 15;
    int base = blockIdx.x * TILE + w * 16;
    int pos = base + ml;
    bool act = pos < E;
    int pp = act ? pos : 0;
    int dn = act ? dsts[pos] : 0;
    int sn = act ? srcs[pos] : 0;

    short8 a[6];
    a[0] = *(const short8*)(hn + (size_t)dn * 64 + q * 8);
    a[1] = *(const short8*)(hn + (size_t)dn * 64 + 32 + q * 8);
    a[2] = *(const short8*)(hn + (size_t)sn * 64 + q * 8);
    a[3] = *(const short8*)(hn + (size_t)sn * 64 + 32 + q * 8);
    short8 e0 = *(const short8*)(e_s + (size_t)pp * 64 + q * 8);
    short8 e1 = *(const short8*)(e_s + (size_t)pp * 64 + 32 + q * 8);

    if (ln_edge) {
        float ev[16];
        float sm = 0.f, sq = 0.f;
#pragma unroll
        for (int i = 0; i < 8; i++) {
            float f0 = bf2f((u16)e0[i]);
            float f1 = bf2f((u16)e1[i]);
            ev[i] = f0; ev[8 + i] = f1;
            sm += f0 + f1; sq += f0 * f0 + f1 * f1;
        }
        sm += __shfl_xor(sm, 16); sm += __shfl_xor(sm, 32);
        sq += __shfl_xor(sq, 16); sq += __shfl_xor(sq, 32);
        float mu = sm * (1.f / 64.f);
        float var = sq * (1.f / 64.f) - mu * mu;
        float inv = rsqrtf(fmaxf(var, 0.f) + LN_EPS);
#pragma unroll
        for (int i = 0; i < 8; i++) {
            int c0 = q * 8 + i, c1 = 32 + q * 8 + i;
            a[4][i] = (short)f2bf((ev[i] - mu) * inv * elng[c0] + elnb[c0]);
            a[5][i] = (short)f2bf((ev[8 + i] - mu) * inv * elng[c1] + elnb[c1]);
        }
    } else {
        a[4] = e0; a[5] = e1;
    }

    float b1c[8], b2c[4];
#pragma unroll
    for (int nt = 0; nt < 8; nt++) b1c[nt] = b1[nt * 16 + ml];
#pragma unroll
    for (int nt = 0; nt < 4; nt++) b2c[nt] = b2[nt * 16 + ml];

    floatx4 acc[8];
#pragma unroll
    for (int nt = 0; nt < 8; nt++) acc[nt] = floatx4{0.f, 0.f, 0.f, 0.f};
#pragma unroll
    for (int kt = 0; kt < 6; kt++) {
#pragma unroll
        for (int nt = 0; nt < 8; nt++) {
            short8 bf = *((const short8*)(W1s + (size_t)((kt * 4 + q) * 128 + nt * 16 + ml) * 8));
            acc[nt] = __builtin_amdgcn_mfma_f32_16x16x32_bf16(a[kt], bf, acc[nt], 0, 0, 0);
        }
    }

    short* arena = sH + w * 16 * HSTR;
#pragma unroll
    for (int nt = 0; nt < 8; nt++) {
#pragma unroll
        for (int r2 = 0; r2 < 4; r2++) {
            float v = fmaxf(acc[nt][r2] + b1c[nt], 0.f);
            ((u16*)arena)[(q * 4 + r2) * HSTR + nt * 16 + ml] = f2bf(v);
        }
    }

    floatx4 acc2[4];
#pragma unroll
    for (int nt = 0; nt < 4; nt++) acc2[nt] = floatx4{0.f, 0.f, 0.f, 0.f};
#pragma unroll
    for (int kt = 0; kt < 4; kt++) {
        short8 ah = *((const short8*)(arena + ml * HSTR + kt * 32 + q * 8));
#pragma unroll
        for (int nt = 0; nt < 4; nt++) {
            short8 bf = *((const short8*)(W2s + (size_t)((kt * 4 + q) * 64 + nt * 16 + ml) * 8));
            acc2[nt] = __builtin_amdgcn_mfma_f32_16x16x32_bf16(ah, bf, acc2[nt], 0, 0, 0);
        }
    }

#pragma unroll
    for (int nt = 0; nt < 4; nt++) {
#pragma unroll
        for (int r2 = 0; r2 < 4; r2++) {
            ((u16*)arena)[(q * 4 + r2) * HSTR + nt * 16 + ml] = f2bf(acc2[nt][r2] + b2c[nt]);
        }
    }
    short8 m0 = *((const short8*)(arena + ml * HSTR + q * 16));
    short8 m1 = *((const short8*)(arena + ml * HSTR + q * 16 + 8));
    if (act) {
        *((short8*)(m_out + (size_t)pos * 64 + q * 16)) = m0;
        *((short8*)(m_out + (size_t)pos * 64 + q * 16 + 8)) = m1;
    }
}

// ---------------- root weight: h = (add_h?h:0) + hn @ Wr  (MFMA) ----------------
__global__ __launch_bounds__(512) void k_root(
    const u16* __restrict__ hn, const u16* __restrict__ Wrs,
    float* __restrict__ h, int add_h, int n) {
    __shared__ short sA[8 * 1024];   // 16 KB
    int t = threadIdx.x;
    int base = blockIdx.x * 128;
    {
        int r = t >> 2, s = t & 3;
        int pos = base + r;
        int g = r >> 4, m = r & 15;
        short* grp = sA + g * 1024;
        bool act = pos < n;
        uint4 z4 = make_uint4(0, 0, 0, 0);
        const uint4* pd = (const uint4*)(hn + (size_t)(act ? pos : 0) * 64);
        uint4 d0 = act ? pd[2 * s] : z4;
        uint4 d1 = act ? pd[2 * s + 1] : z4;
        int ch = (s >> 1) * 4 + (s & 1) * 2;
        *((uint4*)(grp + ch * 128 + m * 8)) = d0;
        *((uint4*)(grp + (ch + 1) * 128 + m * 8)) = d1;
    }
    __syncthreads();
    int w = t >> 6, l = t & 63, q = l >> 4, ml = l & 15;
    short* arena = sA + w * 1024;
    floatx4 acc[4];
#pragma unroll
    for (int nt = 0; nt < 4; nt++) acc[nt] = floatx4{0.f, 0.f, 0.f, 0.f};
#pragma unroll
    for (int kt = 0; kt < 2; kt++) {
        short8 a = *((const short8*)(arena + (kt * 4 + q) * 128 + ml * 8));
#pragma unroll
        for (int nt = 0; nt < 4; nt++) {
            short8 bf = *((const short8*)(Wrs + (size_t)((kt * 4 + q) * 64 + nt * 16 + ml) * 8));
            acc[nt] = __builtin_amdgcn_mfma_f32_16x16x32_bf16(a, bf, acc[nt], 0, 0, 0);
        }
    }
#pragma unroll
    for (int nt = 0; nt < 4; nt++) {
#pragma unroll
        for (int r2 = 0; r2 < 4; r2++) {
            int pos = base + w * 16 + q * 4 + r2;
            if (pos < n) {
                size_t idx = (size_t)pos * 64 + nt * 16 + ml;
                float v = acc[nt][r2];
                h[idx] = add_h ? (h[idx] + v) : v;
            }
        }
    }
}

// ---------------- e += m (vectorized elementwise, bf16) ----------------
__global__ void k_eadd(u16* __restrict__ dst, const u16* __restrict__ src, long nv) {
    long i = (long)blockIdx.x * blockDim.x + threadIdx.x;
    if (i < nv) {
        uint4 a = ((const uint4*)dst)[i];
        uint4 b = ((const uint4*)src)[i];
        u32* pa = (u32*)&a;
        const u32* pb = (const u32*)&b;
        uint4 r;
        u32* pr = (u32*)&r;
#pragma unroll
        for (int k = 0; k < 4; k++) {
            float lo = bf2f((u16)(pa[k] & 0xffffu)) + bf2f((u16)(pb[k] & 0xffffu));
            float hi = bf2f((u16)(pa[k] >> 16)) + bf2f((u16)(pb[k] >> 16));
            pr[k] = (u32)f2bf(lo) | ((u32)f2bf(hi) << 16);
        }
        ((uint4*)dst)[i] = r;
    }
}

// ---------------- aggregation: online softmax over CSR, 2x unrolled ----------------
__global__ __launch_bounds__(256) void k_agg2(
    const u16* __restrict__ m_s, float* __restrict__ h,
    const int* __restrict__ offs, const float* __restrict__ tptr, int tidx,
    int n, int E) {
    int t = threadIdx.x, wid = t >> 6, lane = t & 63;
    float tv = tptr[tidx];
    for (int node = blockIdx.x * 4 + wid; node < n; node += gridDim.x * 4) {
        int p0 = clampi(offs[node], 0, E);
        int p1 = clampi(offs[node + 1], p0, E);
        float M = -1e30f, D = 0.f, S = 0.f;
        int p = p0;
        for (; p + 1 < p1; p += 2) {
            float mv0 = bf2f(m_s[(size_t)p * 64 + lane]);
            float mv1 = bf2f(m_s[(size_t)(p + 1) * 64 + lane]);
            float lg0 = mv0 * tv, lg1 = mv1 * tv;
            // pair partial (independent of running state)
            float Mp = fmaxf(lg0, lg1);
            float a0 = __expf(lg0 - Mp), a1 = __expf(lg1 - Mp);
            float Dp = a0 + a1, Sp = mv0 * a0 + mv1 * a1;
            // merge
            float Mn = fmaxf(M, Mp);
            float xx = __expf(M - Mn), yy = __expf(Mp - Mn);
            D = D * xx + Dp * yy;
            S = S * xx + Sp * yy;
            M = Mn;
        }
        if (p < p1) {
            float mv = bf2f(m_s[(size_t)p * 64 + lane]);
            float lg = mv * tv;
            float Mn = fmaxf(M, lg);
            float xx = __expf(M - Mn), yy = __expf(lg - Mn);
            D = D * xx + yy;
            S = S * xx + mv * yy;
        }
        if (p1 > p0) h[(size_t)node * 64 + lane] += S / D;
    }
}

// ---------------- launcher ----------------
extern "C" void kernel_launch(void* const* d_in, const int* in_sizes, int n_in,
                              void* d_out, int out_size, void* d_ws, size_t ws_size,
                              hipStream_t stream) {
    float* outp = (float*)d_out;
    int FB = (out_size + 255) / 256;

    if (n_in != 17) {
        k_fill<<<FB, 256, 0, stream>>>(outp, out_size, 3.0f);
        return;
    }

    const float* x    = (const float*)d_in[0];
    const int*   ei   = (const int*)d_in[1];
    const float* ea   = (const float*)d_in[2];
    const float* nW   = (const float*)d_in[3];
    const float* nb   = (const float*)d_in[4];
    const float* eW   = (const float*)d_in[5];
    const float* eb   = (const float*)d_in[6];
    const float* cW1  = (const float*)d_in[7];
    const float* cb1  = (const float*)d_in[8];
    const float* cW2  = (const float*)d_in[9];
    const float* cb2  = (const float*)d_in[10];
    const float* cWr  = (const float*)d_in[11];
    const float* ct   = (const float*)d_in[12];
    const float* lng  = (const float*)d_in[13];
    const float* lnb  = (const float*)d_in[14];
    const float* elng = (const float*)d_in[15];
    const float* elnb = (const float*)d_in[16];

    const int n = in_sizes[0] / 128;   // 50000
    const int E = in_sizes[2] / 16;    // 500000

    char* ws = (char*)d_ws;
    size_t o = 0;
    auto alloc = [&](size_t bytes) -> void* {
        void* p = ws + o;
        o += (bytes + 255) & ~(size_t)255;
        return p;
    };
    int*   flag   = (int*)alloc(256);
    int*   deg    = (int*)alloc((size_t)n * 4);
    int*   offs   = (int*)alloc((size_t)(n + 1) * 4);
    int*   cursor = (int*)alloc((size_t)n * 4);
    int*   bsum   = (int*)alloc(256 * 4);
    int*   perm   = (int*)alloc((size_t)E * 4);
    int*   srcs   = (int*)alloc((size_t)E * 4);
    int*   dsts   = (int*)alloc((size_t)E * 4);
    float* h      = (float*)alloc((size_t)n * 64 * 4);
    u16*   hn     = (u16*)alloc((size_t)n * 64 * 2);
    u16*   bufA   = (u16*)alloc((size_t)E * 64 * 2);
    u16*   bufB   = (u16*)alloc((size_t)E * 64 * 2);
    u16*   W1s    = (u16*)alloc((size_t)3 * 24576 * 2);
    u16*   W2s    = (u16*)alloc((size_t)3 * 8192 * 2);
    u16*   Wrs    = (u16*)alloc((size_t)3 * 4096 * 2);

    k_fill<<<FB, 256, 0, stream>>>(outp, out_size, 1.0f);
    if (o > ws_size) {
        k_fill<<<FB, 256, 0, stream>>>(outp, out_size, 2.0f);
        return;
    }

    int SB = (n + 255) / 256;
    k_detect<<<1, 256, 0, stream>>>(ei, E, flag);
    k_zero<<<SB, 256, 0, stream>>>(deg, n);
    k_hist<<<(E + 255) / 256, 256, 0, stream>>>(ei, flag, deg, E, n);
    k_scan1<<<SB, 256, 0, stream>>>(deg, offs, bsum, n);
    k_scan2<<<1, 256, 0, stream>>>(bsum, SB);
    k_scan3<<<SB, 256, 0, stream>>>(offs, bsum, cursor, n, E);
    k_scatter<<<(E + 255) / 256, 256, 0, stream>>>(ei, flag, cursor, perm, srcs, dsts, E, n);
    k_swz<<<(3 * 24576 + 255) / 256, 256, 0, stream>>>(cW1, cW2, cWr, W1s, W2s, Wrs);
    k_node_enc<<<1024, 256, 0, stream>>>(x, nW, nb, h, hn, n);
    k_edge_enc<<<(E * 4 + 255) / 256, 256, 0, stream>>>(ea, perm, eW, eb, bufA, E);

    // Buffer schedule (ping-pong, no copies):
    //  L0: mlp(in=bufA[e0]) -> bufB(m1); agg reads bufB
    //  L1: mlp(in=bufB)     -> bufA(m2); agg reads bufA; eadd: bufB += bufA
    //  L2: mlp(in=bufB)     -> bufA(m3); agg reads bufA
    int MB = (E + TILE - 1) / TILE;
    int RB = (n + 127) / 128;
    int AB = (n + 3) / 4;
    long nv = (long)E * 64 / 8;
    int VB = (int)((nv + 255) / 256);

    const u16* mlp_in[3]  = { bufA, bufB, bufB };
    u16*       mlp_out[3] = { bufB, bufA, bufA };

    for (int i = 0; i < 3; i++) {
        if (i > 0)
            k_lnorm_bf<<<512, 256, 0, stream>>>(h, lng + (size_t)i * 64, lnb + (size_t)i * 64, hn, n);
        k_mlp<<<MB, 512, 0, stream>>>(
            hn, mlp_in[i], dsts, srcs,
            W1s + (size_t)i * 24576, cb1 + (size_t)i * 128,
            W2s + (size_t)i * 8192, cb2 + (size_t)i * 64,
            elng + (size_t)((i > 0) ? (i - 1) : 0) * 64,
            elnb + (size_t)((i > 0) ? (i - 1) : 0) * 64,
            (i > 0) ? 1 : 0, mlp_out[i], E);
        k_root<<<RB, 512, 0, stream>>>(hn, Wrs + (size_t)i * 4096, h, (i > 0) ? 1 : 0, n);
        k_agg2<<<AB, 256, 0, stream>>>(mlp_out[i], h, offs, ct, i, n, E);
        if (i == 1)
            k_eadd<<<VB, 256, 0, stream>>>(bufB, bufA, nv);
    }
    k_lnorm_out<<<512, 256, 0, stream>>>(h, lng, lnb, outp, n);
}

// Round 11
// 712.266 us; speedup vs baseline: 39.6941x; 1.0821x over previous
//
#include <hip/hip_runtime.h>

typedef unsigned short u16;
typedef unsigned int u32;
typedef __attribute__((ext_vector_type(8))) short short8;
typedef __attribute__((ext_vector_type(4))) float floatx4;

#define LN_EPS 1e-5f

__device__ __forceinline__ float bf2f(u16 u) {
    union { u32 i; float f; } v; v.i = ((u32)u) << 16; return v.f;
}
__device__ __forceinline__ u16 f2bf(float f) {
    union { u32 i; float f; } v; v.f = f;
    u32 x = v.i;
    return (u16)((x + 0x7fffu + ((x >> 16) & 1u)) >> 16);
}
__device__ __forceinline__ int clampi(int v, int lo, int hi) {
    return v < lo ? lo : (v > hi ? hi : v);
}

// Diagnostic fill (f32).
__global__ void k_fill(float* __restrict__ out, int nel, float val) {
    int i = blockIdx.x * blockDim.x + threadIdx.x;
    if (i < nel) out[i] = val;
}

// ---------------- preprocessing ----------------
__global__ void k_zero(int* p, int n) {
    int i = blockIdx.x * blockDim.x + threadIdx.x;
    if (i < n) p[i] = 0;
}

__global__ void k_detect(const int* __restrict__ ei, int E, int* __restrict__ flag) {
    __shared__ int any;
    if (threadIdx.x == 0) any = 0;
    __syncthreads();
    int lim = (E < 4096) ? E : 4096;
    int v = 0;
    for (int i = threadIdx.x; i < lim; i += 256) v |= ei[2 * i + 1];
    if (v) atomicOr(&any, 1);
    __syncthreads();
    if (threadIdx.x == 0) flag[0] = (any == 0) ? 1 : 0;
}

__global__ void k_hist(const int* __restrict__ ei, const int* __restrict__ flag,
                       int* __restrict__ deg, int E, int n) {
    int e = blockIdx.x * blockDim.x + threadIdx.x;
    if (e < E) {
        int d = flag[0] ? ei[2 * ((size_t)E + e)] : ei[(size_t)E + e];
        atomicAdd(&deg[clampi(d, 0, n - 1)], 1);
    }
}

__global__ void k_scan1(const int* __restrict__ deg, int* __restrict__ offs,
                        int* __restrict__ bsum, int n) {
    __shared__ int s[256];
    int t = threadIdx.x;
    int i = blockIdx.x * 256 + t;
    int v = (i < n) ? deg[i] : 0;
    s[t] = v; __syncthreads();
    for (int off = 1; off < 256; off <<= 1) {
        int x = (t >= off) ? s[t - off] : 0;
        __syncthreads();
        s[t] += x;
        __syncthreads();
    }
    if (i < n) offs[i] = s[t] - v;
    if (t == 255) bsum[blockIdx.x] = s[255];
}

__global__ void k_scan2(int* bsum, int nb) {
    __shared__ int s[256];
    int t = threadIdx.x;
    int v = (t < nb) ? bsum[t] : 0;
    s[t] = v; __syncthreads();
    for (int off = 1; off < 256; off <<= 1) {
        int x = (t >= off) ? s[t - off] : 0;
        __syncthreads();
        s[t] += x;
        __syncthreads();
    }
    if (t < nb) bsum[t] = s[t] - v;
}

__global__ void k_scan3(int* __restrict__ offs, const int* __restrict__ bsum,
                        int* __restrict__ cursor, int n, int E) {
    int i = blockIdx.x * 256 + threadIdx.x;
    if (i < n) {
        int v = offs[i] + bsum[blockIdx.x];
        offs[i] = v;
        cursor[i] = v;
    }
    if (i == 0) offs[n] = E;
}

__global__ void k_scatter(const int* __restrict__ ei, const int* __restrict__ flag,
                          int* __restrict__ cursor,
                          int* __restrict__ perm, int* __restrict__ srcs,
                          int* __restrict__ dsts, int E, int n) {
    int e = blockIdx.x * blockDim.x + threadIdx.x;
    if (e < E) {
        int sv, dv;
        if (flag[0]) {
            sv = ei[2 * (size_t)e];
            dv = ei[2 * ((size_t)E + e)];
        } else {
            sv = ei[e];
            dv = ei[(size_t)E + e];
        }
        sv = clampi(sv, 0, n - 1);
        dv = clampi(dv, 0, n - 1);
        int p = clampi(atomicAdd(&cursor[dv], 1), 0, E - 1);
        perm[p] = e;
        srcs[p] = sv;
        dsts[p] = dv;
    }
}

// Pre-swizzle f32 weights into bf16 MFMA B-fragment order:
// B[k][n], k = kt*32 + q*8 + j  ->  idx = ((kt*4+q)*N + n)*8 + j
__global__ void k_swz(const float* __restrict__ W1, const float* __restrict__ W2,
                      const float* __restrict__ Wr, const float* __restrict__ nW,
                      u16* __restrict__ W1s, u16* __restrict__ W2s,
                      u16* __restrict__ Wrs, u16* __restrict__ nWs) {
    int i = blockIdx.x * blockDim.x + threadIdx.x;
    if (i < 3 * 24576) {
        int l = i / 24576, rem = i % 24576;
        int k = rem / 128, n = rem % 128;
        int kt = k >> 5, q = (k >> 3) & 3, j = k & 7;
        W1s[l * 24576 + ((kt * 4 + q) * 128 + n) * 8 + j] = f2bf(W1[i]);
    }
    if (i < 3 * 8192) {
        int l = i / 8192, rem = i % 8192;
        int k = rem / 64, n = rem % 64;
        int kt = k >> 5, q = (k >> 3) & 3, j = k & 7;
        W2s[l * 8192 + ((kt * 4 + q) * 64 + n) * 8 + j] = f2bf(W2[i]);
    }
    if (i < 3 * 4096) {
        int l = i / 4096, rem = i % 4096;
        int k = rem / 64, n = rem % 64;
        int kt = k >> 5, q = (k >> 3) & 3, j = k & 7;
        Wrs[l * 4096 + ((kt * 4 + q) * 64 + n) * 8 + j] = f2bf(Wr[i]);
    }
    if (i < 8192) {
        int k = i / 64, n = i % 64;
        int kt = k >> 5, q = (k >> 3) & 3, j = k & 7;
        nWs[((kt * 4 + q) * 64 + n) * 8 + j] = f2bf(nW[i]);
    }
}

// ---------------- node encoder (MFMA, LDS-free, barrier-free) ----------------
// 512 threads = 8 waves; wave handles 16 rows. A-frags converted f32->bf16 in regs.
__global__ __launch_bounds__(512) void k_node_enc(
    const float* __restrict__ x, const u16* __restrict__ nWs, const float* __restrict__ bias,
    float* __restrict__ h, u16* __restrict__ hn, int n) {
    int t = threadIdx.x;
    int w = t >> 6, l = t & 63, q = l >> 4, ml = l & 15;
    int wbase = blockIdx.x * 128 + w * 16;
    int rin = wbase + ml;
    int rr = (rin < n) ? rin : 0;
    const float* xr = x + (size_t)rr * 128;
    short8 a[4];
#pragma unroll
    for (int kt = 0; kt < 4; kt++) {
        float4 f0 = *((const float4*)(xr + kt * 32 + q * 8));
        float4 f1 = *((const float4*)(xr + kt * 32 + q * 8 + 4));
        a[kt][0] = (short)f2bf(f0.x); a[kt][1] = (short)f2bf(f0.y);
        a[kt][2] = (short)f2bf(f0.z); a[kt][3] = (short)f2bf(f0.w);
        a[kt][4] = (short)f2bf(f1.x); a[kt][5] = (short)f2bf(f1.y);
        a[kt][6] = (short)f2bf(f1.z); a[kt][7] = (short)f2bf(f1.w);
    }
    float bc[4];
#pragma unroll
    for (int nt = 0; nt < 4; nt++) bc[nt] = bias[nt * 16 + ml];
    floatx4 acc[4];
#pragma unroll
    for (int nt = 0; nt < 4; nt++) acc[nt] = floatx4{0.f, 0.f, 0.f, 0.f};
#pragma unroll
    for (int kt = 0; kt < 4; kt++) {
#pragma unroll
        for (int nt = 0; nt < 4; nt++) {
            short8 bf = *((const short8*)(nWs + (size_t)((kt * 4 + q) * 64 + nt * 16 + ml) * 8));
            acc[nt] = __builtin_amdgcn_mfma_f32_16x16x32_bf16(a[kt], bf, acc[nt], 0, 0, 0);
        }
    }
#pragma unroll
    for (int nt = 0; nt < 4; nt++) {
#pragma unroll
        for (int r2 = 0; r2 < 4; r2++) {
            int pos = wbase + q * 4 + r2;
            if (pos < n) {
                float v = acc[nt][r2] + bc[nt];
                size_t idx = (size_t)pos * 64 + nt * 16 + ml;
                h[idx] = v;
                hn[idx] = f2bf(v);
            }
        }
    }
}

// Thread-per-(edge, 16-ch quarter): fully independent threads, no shuffles.
__global__ __launch_bounds__(256) void k_edge_enc(
    const float* __restrict__ ea, const int* __restrict__ perm,
    const float* __restrict__ W, const float* __restrict__ bias,
    u16* __restrict__ e_s, int E) {
    __shared__ float4 sW4[16 * 16];   // W[16][64] as float4 [k][c/4], 4 KB
    int t = threadIdx.x;
    if (t < 256) sW4[t] = ((const float4*)W)[t];
    __syncthreads();
    int gid = blockIdx.x * 256 + t;
    int eidx = gid >> 2, qq = gid & 3;
    if (eidx >= E) return;
    int e = perm[eidx];
    const float4* row4 = (const float4*)(ea + (size_t)e * 16);
    float4 r4[4];
    r4[0] = row4[0]; r4[1] = row4[1]; r4[2] = row4[2]; r4[3] = row4[3];
    const float* row = (const float*)r4;
    float4 acc[4];
#pragma unroll
    for (int j = 0; j < 4; j++) acc[j] = ((const float4*)bias)[qq * 4 + j];
#pragma unroll
    for (int k = 0; k < 16; k++) {
        float rv = row[k];
#pragma unroll
        for (int j = 0; j < 4; j++) {
            float4 wv = sW4[k * 16 + qq * 4 + j];
            acc[j].x += rv * wv.x; acc[j].y += rv * wv.y;
            acc[j].z += rv * wv.z; acc[j].w += rv * wv.w;
        }
    }
    u32 pk[8];
#pragma unroll
    for (int j = 0; j < 4; j++) {
        pk[2 * j]     = (u32)f2bf(acc[j].x) | ((u32)f2bf(acc[j].y) << 16);
        pk[2 * j + 1] = (u32)f2bf(acc[j].z) | ((u32)f2bf(acc[j].w) << 16);
    }
    uint4* outp = (uint4*)(e_s + (size_t)eidx * 64 + qq * 16);
    outp[0] = make_uint4(pk[0], pk[1], pk[2], pk[3]);
    outp[1] = make_uint4(pk[4], pk[5], pk[6], pk[7]);
}

// ---------------- layernorm: bf16-out (hn producer) and f32-out (final) ----------------
__global__ __launch_bounds__(256) void k_lnorm_bf(
    const float* __restrict__ h, const float* __restrict__ g, const float* __restrict__ b,
    u16* __restrict__ out, int n) {
    int t = threadIdx.x, wid = t >> 6, lane = t & 63;
    float gc = g[lane], bc = b[lane];
    for (int row = blockIdx.x * 4 + wid; row < n; row += gridDim.x * 4) {
        float v = h[(size_t)row * 64 + lane];
        float s = v;
#pragma unroll
        for (int o = 32; o > 0; o >>= 1) s += __shfl_xor(s, o);
        float mu = s * (1.f / 64.f);
        float d = v - mu;
        float s2 = d * d;
#pragma unroll
        for (int o = 32; o > 0; o >>= 1) s2 += __shfl_xor(s2, o);
        float inv = rsqrtf(s2 * (1.f / 64.f) + LN_EPS);
        float r = fmaxf(d * inv * gc + bc, 0.f);
        out[(size_t)row * 64 + lane] = f2bf(r);
    }
}

__global__ __launch_bounds__(256) void k_lnorm_out(
    const float* __restrict__ h, const float* __restrict__ g, const float* __restrict__ b,
    float* __restrict__ out, int n) {
    int t = threadIdx.x, wid = t >> 6, lane = t & 63;
    float gc = g[lane], bc = b[lane];
    for (int row = blockIdx.x * 4 + wid; row < n; row += gridDim.x * 4) {
        float v = h[(size_t)row * 64 + lane];
        float s = v;
#pragma unroll
        for (int o = 32; o > 0; o >>= 1) s += __shfl_xor(s, o);
        float mu = s * (1.f / 64.f);
        float d = v - mu;
        float s2 = d * d;
#pragma unroll
        for (int o = 32; o > 0; o >>= 1) s2 += __shfl_xor(s2, o);
        float inv = rsqrtf(s2 * (1.f / 64.f) + LN_EPS);
        out[(size_t)row * 64 + lane] = fmaxf(d * inv * gc + bc, 0.f);
    }
}

// ---------------- edge MLP (MFMA, barrier-free, single-tile — R8 proven) ----------------
#define TILE 128
#define HSTR 136
__global__ __launch_bounds__(512, 4) void k_mlp(
    const u16* __restrict__ hn, const u16* __restrict__ e_s,
    const int* __restrict__ dsts, const int* __restrict__ srcs,
    const u16* __restrict__ W1s, const float* __restrict__ b1,
    const u16* __restrict__ W2s, const float* __restrict__ b2,
    const float* __restrict__ elng, const float* __restrict__ elnb,
    int ln_edge, u16* __restrict__ m_out, int E) {
    __shared__ short sH[8 * 16 * HSTR];   // 34 KB

    int t = threadIdx.x;
    int w = t >> 6, l = t & 63, q = l >> 4, ml = l & 15;
    int base = blockIdx.x * TILE + w * 16;
    int pos = base + ml;
    bool act = pos < E;
    int pp = act ? pos : 0;
    int dn = act ? dsts[pos] : 0;
    int sn = act ? srcs[pos] : 0;

    short8 a[6];
    a[0] = *(const short8*)(hn + (size_t)dn * 64 + q * 8);
    a[1] = *(const short8*)(hn + (size_t)dn * 64 + 32 + q * 8);
    a[2] = *(const short8*)(hn + (size_t)sn * 64 + q * 8);
    a[3] = *(const short8*)(hn + (size_t)sn * 64 + 32 + q * 8);
    short8 e0 = *(const short8*)(e_s + (size_t)pp * 64 + q * 8);
    short8 e1 = *(const short8*)(e_s + (size_t)pp * 64 + 32 + q * 8);

    if (ln_edge) {
        float ev[16];
        float sm = 0.f, sq = 0.f;
#pragma unroll
        for (int i = 0; i < 8; i++) {
            float f0 = bf2f((u16)e0[i]);
            float f1 = bf2f((u16)e1[i]);
            ev[i] = f0; ev[8 + i] = f1;
            sm += f0 + f1; sq += f0 * f0 + f1 * f1;
        }
        sm += __shfl_xor(sm, 16); sm += __shfl_xor(sm, 32);
        sq += __shfl_xor(sq, 16); sq += __shfl_xor(sq, 32);
        float mu = sm * (1.f / 64.f);
        float var = sq * (1.f / 64.f) - mu * mu;
        float inv = rsqrtf(fmaxf(var, 0.f) + LN_EPS);
#pragma unroll
        for (int i = 0; i < 8; i++) {
            int c0 = q * 8 + i, c1 = 32 + q * 8 + i;
            a[4][i] = (short)f2bf((ev[i] - mu) * inv * elng[c0] + elnb[c0]);
            a[5][i] = (short)f2bf((ev[8 + i] - mu) * inv * elng[c1] + elnb[c1]);
        }
    } else {
        a[4] = e0; a[5] = e1;
    }

    float b1c[8], b2c[4];
#pragma unroll
    for (int nt = 0; nt < 8; nt++) b1c[nt] = b1[nt * 16 + ml];
#pragma unroll
    for (int nt = 0; nt < 4; nt++) b2c[nt] = b2[nt * 16 + ml];

    floatx4 acc[8];
#pragma unroll
    for (int nt = 0; nt < 8; nt++) acc[nt] = floatx4{0.f, 0.f, 0.f, 0.f};
#pragma unroll
    for (int kt = 0; kt < 6; kt++) {
#pragma unroll
        for (int nt = 0; nt < 8; nt++) {
            short8 bf = *((const short8*)(W1s + (size_t)((kt * 4 + q) * 128 + nt * 16 + ml) * 8));
            acc[nt] = __builtin_amdgcn_mfma_f32_16x16x32_bf16(a[kt], bf, acc[nt], 0, 0, 0);
        }
    }

    short* arena = sH + w * 16 * HSTR;
#pragma unroll
    for (int nt = 0; nt < 8; nt++) {
#pragma unroll
        for (int r2 = 0; r2 < 4; r2++) {
            float v = fmaxf(acc[nt][r2] + b1c[nt], 0.f);
            ((u16*)arena)[(q * 4 + r2) * HSTR + nt * 16 + ml] = f2bf(v);
        }
    }

    floatx4 acc2[4];
#pragma unroll
    for (int nt = 0; nt < 4; nt++) acc2[nt] = floatx4{0.f, 0.f, 0.f, 0.f};
#pragma unroll
    for (int kt = 0; kt < 4; kt++) {
        short8 ah = *((const short8*)(arena + ml * HSTR + kt * 32 + q * 8));
#pragma unroll
        for (int nt = 0; nt < 4; nt++) {
            short8 bf = *((const short8*)(W2s + (size_t)((kt * 4 + q) * 64 + nt * 16 + ml) * 8));
            acc2[nt] = __builtin_amdgcn_mfma_f32_16x16x32_bf16(ah, bf, acc2[nt], 0, 0, 0);
        }
    }

#pragma unroll
    for (int nt = 0; nt < 4; nt++) {
#pragma unroll
        for (int r2 = 0; r2 < 4; r2++) {
            ((u16*)arena)[(q * 4 + r2) * HSTR + nt * 16 + ml] = f2bf(acc2[nt][r2] + b2c[nt]);
        }
    }
    short8 m0 = *((const short8*)(arena + ml * HSTR + q * 16));
    short8 m1 = *((const short8*)(arena + ml * HSTR + q * 16 + 8));
    if (act) {
        *((short8*)(m_out + (size_t)pos * 64 + q * 16)) = m0;
        *((short8*)(m_out + (size_t)pos * 64 + q * 16 + 8)) = m1;
    }
}

// ---------------- root weight: h = (add_h?h:0) + hn @ Wr  (MFMA) ----------------
__global__ __launch_bounds__(512) void k_root(
    const u16* __restrict__ hn, const u16* __restrict__ Wrs,
    float* __restrict__ h, int add_h, int n) {
    __shared__ short sA[8 * 1024];   // 16 KB
    int t = threadIdx.x;
    int base = blockIdx.x * 128;
    {
        int r = t >> 2, s = t & 3;
        int pos = base + r;
        int g = r >> 4, m = r & 15;
        short* grp = sA + g * 1024;
        bool act = pos < n;
        uint4 z4 = make_uint4(0, 0, 0, 0);
        const uint4* pd = (const uint4*)(hn + (size_t)(act ? pos : 0) * 64);
        uint4 d0 = act ? pd[2 * s] : z4;
        uint4 d1 = act ? pd[2 * s + 1] : z4;
        int ch = (s >> 1) * 4 + (s & 1) * 2;
        *((uint4*)(grp + ch * 128 + m * 8)) = d0;
        *((uint4*)(grp + (ch + 1) * 128 + m * 8)) = d1;
    }
    __syncthreads();
    int w = t >> 6, l = t & 63, q = l >> 4, ml = l & 15;
    short* arena = sA + w * 1024;
    floatx4 acc[4];
#pragma unroll
    for (int nt = 0; nt < 4; nt++) acc[nt] = floatx4{0.f, 0.f, 0.f, 0.f};
#pragma unroll
    for (int kt = 0; kt < 2; kt++) {
        short8 a = *((const short8*)(arena + (kt * 4 + q) * 128 + ml * 8));
#pragma unroll
        for (int nt = 0; nt < 4; nt++) {
            short8 bf = *((const short8*)(Wrs + (size_t)((kt * 4 + q) * 64 + nt * 16 + ml) * 8));
            acc[nt] = __builtin_amdgcn_mfma_f32_16x16x32_bf16(a, bf, acc[nt], 0, 0, 0);
        }
    }
#pragma unroll
    for (int nt = 0; nt < 4; nt++) {
#pragma unroll
        for (int r2 = 0; r2 < 4; r2++) {
            int pos = base + w * 16 + q * 4 + r2;
            if (pos < n) {
                size_t idx = (size_t)pos * 64 + nt * 16 + ml;
                float v = acc[nt][r2];
                h[idx] = add_h ? (h[idx] + v) : v;
            }
        }
    }
}

// ---------------- e += m (vectorized elementwise, bf16) ----------------
__global__ void k_eadd(u16* __restrict__ dst, const u16* __restrict__ src, long nv) {
    long i = (long)blockIdx.x * blockDim.x + threadIdx.x;
    if (i < nv) {
        uint4 a = ((const uint4*)dst)[i];
        uint4 b = ((const uint4*)src)[i];
        u32* pa = (u32*)&a;
        const u32* pb = (const u32*)&b;
        uint4 r;
        u32* pr = (u32*)&r;
#pragma unroll
        for (int k = 0; k < 4; k++) {
            float lo = bf2f((u16)(pa[k] & 0xffffu)) + bf2f((u16)(pb[k] & 0xffffu));
            float hi = bf2f((u16)(pa[k] >> 16)) + bf2f((u16)(pb[k] >> 16));
            pr[k] = (u32)f2bf(lo) | ((u32)f2bf(hi) << 16);
        }
        ((uint4*)dst)[i] = r;
    }
}

// ---------------- aggregation: online softmax over CSR, 2x unrolled ----------------
__global__ __launch_bounds__(256) void k_agg2(
    const u16* __restrict__ m_s, float* __restrict__ h,
    const int* __restrict__ offs, const float* __restrict__ tptr, int tidx,
    int n, int E) {
    int t = threadIdx.x, wid = t >> 6, lane = t & 63;
    float tv = tptr[tidx];
    for (int node = blockIdx.x * 4 + wid; node < n; node += gridDim.x * 4) {
        int p0 = clampi(offs[node], 0, E);
        int p1 = clampi(offs[node + 1], p0, E);
        float M = -1e30f, D = 0.f, S = 0.f;
        int p = p0;
        for (; p + 1 < p1; p += 2) {
            float mv0 = bf2f(m_s[(size_t)p * 64 + lane]);
            float mv1 = bf2f(m_s[(size_t)(p + 1) * 64 + lane]);
            float lg0 = mv0 * tv, lg1 = mv1 * tv;
            float Mp = fmaxf(lg0, lg1);
            float a0 = __expf(lg0 - Mp), a1 = __expf(lg1 - Mp);
            float Dp = a0 + a1, Sp = mv0 * a0 + mv1 * a1;
            float Mn = fmaxf(M, Mp);
            float xx = __expf(M - Mn), yy = __expf(Mp - Mn);
            D = D * xx + Dp * yy;
            S = S * xx + Sp * yy;
            M = Mn;
        }
        if (p < p1) {
            float mv = bf2f(m_s[(size_t)p * 64 + lane]);
            float lg = mv * tv;
            float Mn = fmaxf(M, lg);
            float xx = __expf(M - Mn), yy = __expf(lg - Mn);
            D = D * xx + yy;
            S = S * xx + mv * yy;
        }
        if (p1 > p0) h[(size_t)node * 64 + lane] += S / D;
    }
}

// ---------------- launcher ----------------
extern "C" void kernel_launch(void* const* d_in, const int* in_sizes, int n_in,
                              void* d_out, int out_size, void* d_ws, size_t ws_size,
                              hipStream_t stream) {
    float* outp = (float*)d_out;
    int FB = (out_size + 255) / 256;

    if (n_in != 17) {
        k_fill<<<FB, 256, 0, stream>>>(outp, out_size, 3.0f);
        return;
    }

    const float* x    = (const float*)d_in[0];
    const int*   ei   = (const int*)d_in[1];
    const float* ea   = (const float*)d_in[2];
    const float* nW   = (const float*)d_in[3];
    const float* nb   = (const float*)d_in[4];
    const float* eW   = (const float*)d_in[5];
    const float* eb   = (const float*)d_in[6];
    const float* cW1  = (const float*)d_in[7];
    const float* cb1  = (const float*)d_in[8];
    const float* cW2  = (const float*)d_in[9];
    const float* cb2  = (const float*)d_in[10];
    const float* cWr  = (const float*)d_in[11];
    const float* ct   = (const float*)d_in[12];
    const float* lng  = (const float*)d_in[13];
    const float* lnb  = (const float*)d_in[14];
    const float* elng = (const float*)d_in[15];
    const float* elnb = (const float*)d_in[16];

    const int n = in_sizes[0] / 128;   // 50000
    const int E = in_sizes[2] / 16;    // 500000

    char* ws = (char*)d_ws;
    size_t o = 0;
    auto alloc = [&](size_t bytes) -> void* {
        void* p = ws + o;
        o += (bytes + 255) & ~(size_t)255;
        return p;
    };
    int*   flag   = (int*)alloc(256);
    int*   deg    = (int*)alloc((size_t)n * 4);
    int*   offs   = (int*)alloc((size_t)(n + 1) * 4);
    int*   cursor = (int*)alloc((size_t)n * 4);
    int*   bsum   = (int*)alloc(256 * 4);
    int*   perm   = (int*)alloc((size_t)E * 4);
    int*   srcs   = (int*)alloc((size_t)E * 4);
    int*   dsts   = (int*)alloc((size_t)E * 4);
    float* h      = (float*)alloc((size_t)n * 64 * 4);
    u16*   hn     = (u16*)alloc((size_t)n * 64 * 2);
    u16*   bufA   = (u16*)alloc((size_t)E * 64 * 2);
    u16*   bufB   = (u16*)alloc((size_t)E * 64 * 2);
    u16*   W1s    = (u16*)alloc((size_t)3 * 24576 * 2);
    u16*   W2s    = (u16*)alloc((size_t)3 * 8192 * 2);
    u16*   Wrs    = (u16*)alloc((size_t)3 * 4096 * 2);
    u16*   nWs    = (u16*)alloc((size_t)8192 * 2);

    k_fill<<<FB, 256, 0, stream>>>(outp, out_size, 1.0f);
    if (o > ws_size) {
        k_fill<<<FB, 256, 0, stream>>>(outp, out_size, 2.0f);
        return;
    }

    int SB = (n + 255) / 256;
    k_detect<<<1, 256, 0, stream>>>(ei, E, flag);
    k_zero<<<SB, 256, 0, stream>>>(deg, n);
    k_hist<<<(E + 255) / 256, 256, 0, stream>>>(ei, flag, deg, E, n);
    k_scan1<<<SB, 256, 0, stream>>>(deg, offs, bsum, n);
    k_scan2<<<1, 256, 0, stream>>>(bsum, SB);
    k_scan3<<<SB, 256, 0, stream>>>(offs, bsum, cursor, n, E);
    k_scatter<<<(E + 255) / 256, 256, 0, stream>>>(ei, flag, cursor, perm, srcs, dsts, E, n);
    k_swz<<<(3 * 24576 + 255) / 256, 256, 0, stream>>>(cW1, cW2, cWr, nW, W1s, W2s, Wrs, nWs);
    k_node_enc<<<(n + 127) / 128, 512, 0, stream>>>(x, nWs, nb, h, hn, n);
    k_edge_enc<<<(E * 4 + 255) / 256, 256, 0, stream>>>(ea, perm, eW, eb, bufA, E);

    // Buffer schedule (ping-pong, no copies) — R8 proven:
    //  L0: mlp(in=bufA) -> bufB(m1); agg reads bufB
    //  L1: mlp(in=bufB) -> bufA(m2); agg reads bufA; eadd: bufB += bufA
    //  L2: mlp(in=bufB) -> bufA(m3); agg reads bufA
    int MB = (E + TILE - 1) / TILE;
    int RB = (n + 127) / 128;
    int AB = (n + 3) / 4;
    long nv = (long)E * 64 / 8;
    int VB = (int)((nv + 255) / 256);

    const u16* mlp_in[3]  = { bufA, bufB, bufB };
    u16*       mlp_out[3] = { bufB, bufA, bufA };

    for (int i = 0; i < 3; i++) {
        if (i > 0)
            k_lnorm_bf<<<512, 256, 0, stream>>>(h, lng + (size_t)i * 64, lnb + (size_t)i * 64, hn, n);
        k_mlp<<<MB, 512, 0, stream>>>(
            hn, mlp_in[i], dsts, srcs,
            W1s + (size_t)i * 24576, cb1 + (size_t)i * 128,
            W2s + (size_t)i * 8192, cb2 + (size_t)i * 64,
            elng + (size_t)((i > 0) ? (i - 1) : 0) * 64,
            elnb + (size_t)((i > 0) ? (i - 1) : 0) * 64,
            (i > 0) ? 1 : 0, mlp_out[i], E);
        k_root<<<RB, 512, 0, stream>>>(hn, Wrs + (size_t)i * 4096, h, (i > 0) ? 1 : 0, n);
        k_agg2<<<AB, 256, 0, stream>>>(mlp_out[i], h, offs, ct, i, n, E);
        if (i == 1)
            k_eadd<<<VB, 256, 0, stream>>>(bufB, bufA, nv);
    }
    k_lnorm_out<<<512, 256, 0, stream>>>(h, lng, lnb, outp, n);
}